// Round 1
// baseline (4060.064 us; speedup 1.0000x reference)
//
#include <hip/hip_runtime.h>
#include <hip/hip_bf16.h>

// ---------------- constants (fixed by problem) ----------------
#define Nn_   120000
#define F_    256
#define H_    256
#define L_    64
#define EMP_  1000000
#define E_    200000
#define P0_   60000
#define P1_   80000
#define P2_   100000
#define PROXW 0.3f

// ---------------- CSR build ----------------
__global__ void k_count(const int* __restrict__ dst, int* __restrict__ cnt, int n) {
    int e = blockIdx.x * 256 + threadIdx.x;
    if (e < n) atomicAdd(&cnt[dst[e]], 1);
}

__global__ void k_block_reduce(const int* __restrict__ cnt, int* __restrict__ bsum, int n) {
    __shared__ int s[256];
    int i = blockIdx.x * 256 + threadIdx.x;
    s[threadIdx.x] = (i < n) ? cnt[i] : 0;
    __syncthreads();
    for (int o = 128; o > 0; o >>= 1) {
        if (threadIdx.x < o) s[threadIdx.x] += s[threadIdx.x + o];
        __syncthreads();
    }
    if (threadIdx.x == 0) bsum[blockIdx.x] = s[0];
}

__global__ void k_scan_bsum(int* bsum, int nb) {
    if (threadIdx.x == 0 && blockIdx.x == 0) {
        int acc = 0;
        for (int i = 0; i < nb; i++) { int v = bsum[i]; bsum[i] = acc; acc += v; }
    }
}

__global__ void k_scan_final(const int* __restrict__ cnt, const int* __restrict__ bsum,
                             int* __restrict__ rowp, int n, int etot) {
    __shared__ int s[256];
    int tid = threadIdx.x;
    int i = blockIdx.x * 256 + tid;
    int v = (i < n) ? cnt[i] : 0;
    s[tid] = v;
    __syncthreads();
    for (int o = 1; o < 256; o <<= 1) {
        int t = 0;
        if (tid >= o) t = s[tid - o];
        __syncthreads();
        s[tid] += t;
        __syncthreads();
    }
    if (i < n) rowp[i] = bsum[blockIdx.x] + s[tid] - v;
    if (i == 0 && blockIdx.x == 0) rowp[n] = etot;
}

__global__ void k_fill(const int* __restrict__ src, const int* __restrict__ dst,
                       const int* __restrict__ rowp, int* __restrict__ fill,
                       int* __restrict__ csr, int n) {
    int e = blockIdx.x * 256 + threadIdx.x;
    if (e < n) {
        int d = dst[e];
        int p = atomicAdd(&fill[d], 1);
        csr[rowp[d] + p] = src[e];
    }
}

__global__ void k_dinv(const int* __restrict__ cnt, float* __restrict__ dinv, int n) {
    int i = blockIdx.x * 256 + threadIdx.x;
    if (i < n) dinv[i] = rsqrtf((float)cnt[i] + 1.0f);
}

// ---------------- generic tiled f32 GEMM ----------------
// C[M x N] = op( [ACC: C +] A[M x K] @ B + [BIAS: bias] ), op = TANH? tanh : id
// TRANSB: B is [N x K] row-major (use B[n][k]); else B is [K x N].
#define TM 64
#define TN 64
#define TK 16

template <bool TRANSB, bool ACC, bool BIAS, bool TANH>
__global__ void gemm_tiled(const float* __restrict__ A, const float* __restrict__ B,
                           const float* __restrict__ bias, float* __restrict__ C,
                           int M, int K, int N) {
    __shared__ float As[TK][TM + 4];
    __shared__ float Bs[TK][TN + 4];
    int tid = threadIdx.x;
    int tx = tid & 15, ty = tid >> 4;
    int row0 = blockIdx.y * TM, col0 = blockIdx.x * TN;
    int lr = tid >> 2;            // 0..63
    int lc4 = (tid & 3) * 4;      // 0,4,8,12
    float acc[4][4] = {};
    for (int k0 = 0; k0 < K; k0 += TK) {
        // A tile 64x16
        {
            int gr = row0 + lr;
            float4 v = make_float4(0.f, 0.f, 0.f, 0.f);
            if (gr < M) v = *(const float4*)(A + (size_t)gr * K + k0 + lc4);
            As[lc4 + 0][lr] = v.x; As[lc4 + 1][lr] = v.y;
            As[lc4 + 2][lr] = v.z; As[lc4 + 3][lr] = v.w;
        }
        // B tile 16x64
        {
            int n = tid & 63, kk0 = tid >> 6;
#pragma unroll
            for (int p = 0; p < 4; p++) {
                int kk = kk0 + p * 4;
                if (TRANSB)
                    Bs[kk][n] = B[(size_t)(col0 + n) * K + k0 + kk];
                else
                    Bs[kk][n] = B[(size_t)(k0 + kk) * N + col0 + n];
            }
        }
        __syncthreads();
#pragma unroll
        for (int kk = 0; kk < TK; kk++) {
            float4 a = *(const float4*)&As[kk][ty * 4];
            float4 b = *(const float4*)&Bs[kk][tx * 4];
            float av[4] = {a.x, a.y, a.z, a.w};
            float bv[4] = {b.x, b.y, b.z, b.w};
#pragma unroll
            for (int i = 0; i < 4; i++)
#pragma unroll
                for (int j = 0; j < 4; j++) acc[i][j] += av[i] * bv[j];
        }
        __syncthreads();
    }
#pragma unroll
    for (int i = 0; i < 4; i++) {
        int r = row0 + ty * 4 + i;
        if (r >= M) continue;
#pragma unroll
        for (int j = 0; j < 4; j++) {
            int c = col0 + tx * 4 + j;
            float v = acc[i][j];
            if (ACC) v += C[(size_t)r * N + c];
            if (BIAS) v += bias[c];
            if (TANH) v = tanhf(v);
            C[(size_t)r * N + c] = v;
        }
    }
}

// ---------------- GCN aggregation (gather over CSR, +self loop, bias, tanh) ----------------
__global__ void k_aggregate(const float* __restrict__ xw, const int* __restrict__ rowp,
                            const int* __restrict__ csr, const float* __restrict__ dinv,
                            const float* __restrict__ bias, float* __restrict__ out) {
    int v = blockIdx.x;
    int j = threadIdx.x;  // 256 cols
    float acc = 0.f;
    int beg = rowp[v], end = rowp[v + 1];
    for (int p = beg; p < end; ++p) {
        int s = csr[p];
        acc += xw[(size_t)s * H_ + j] * dinv[s];
    }
    float dv = dinv[v];
    acc = acc * dv + xw[(size_t)v * H_ + j] * dv * dv;
    out[(size_t)v * H_ + j] = tanhf(acc + bias[j]);
}

// ---------------- attention: u[n] = sum_s softmax_s(t[n].stack_s[n]/16) stack_s[n] ----------------
__global__ void k_attn_u(const float* emb, const float* t, const float* p0,
                         const float* p1, const float* p2, float* u) {
    int tid = threadIdx.x;
    int lane = tid & 63, w = tid >> 6;
    int n = blockIdx.x * 4 + w;
    const float4* e4 = (const float4*)emb;
    float4* u4 = (float4*)u;
    size_t base = (size_t)n * 64 + lane;
    if (n >= P2_) { u4[base] = e4[base]; return; }
    const float* st[4];
    int S;
    if (n < P0_)      { st[0] = p0; st[1] = p1; st[2] = p2; st[3] = emb; S = 4; }
    else if (n < P1_) { st[0] = p1; st[1] = p2; st[2] = emb; S = 3; }
    else              { st[0] = p2; st[1] = emb; S = 2; }
    float4 tv = ((const float4*)t)[base];
    float4 sv[4];
    float lg[4];
    for (int s = 0; s < S; s++) {
        sv[s] = ((const float4*)st[s])[base];
        float d = tv.x * sv[s].x + tv.y * sv[s].y + tv.z * sv[s].z + tv.w * sv[s].w;
        for (int o = 32; o > 0; o >>= 1) d += __shfl_xor(d, o);
        lg[s] = d * 0.0625f;  // /sqrt(256)
    }
    float m = lg[0];
    for (int s = 1; s < S; s++) m = fmaxf(m, lg[s]);
    float wgt[4], den = 0.f;
    for (int s = 0; s < S; s++) { wgt[s] = expf(lg[s] - m); den += wgt[s]; }
    float inv = 1.f / den;
    float4 o = make_float4(0.f, 0.f, 0.f, 0.f);
    for (int s = 0; s < S; s++) {
        float ws = wgt[s] * inv;
        o.x += ws * sv[s].x; o.y += ws * sv[s].y; o.z += ws * sv[s].z; o.w += ws * sv[s].w;
    }
    u4[base] = o;
}

// ---------------- sym = 0.5*(W + W^T) ----------------
__global__ void k_sym(const float* __restrict__ W, float* __restrict__ sym) {
    int i = blockIdx.x * 256 + threadIdx.x;
    int r = i >> 8, c = i & 255;
    sym[i] = 0.5f * (W[r * 256 + c] + W[c * 256 + r]);
}

__global__ void k_sumb(const float* __restrict__ b, float* __restrict__ out) {
    __shared__ float s[256];
    int tid = threadIdx.x;
    s[tid] = b[tid];
    __syncthreads();
    for (int o = 128; o > 0; o >>= 1) {
        if (tid < o) s[tid] += s[tid + o];
        __syncthreads();
    }
    if (tid == 0) out[0] = s[0];
}

// ---------------- fused edge MLP (meanmax-gathered A, layer1 tanh, dot w2, atomic) ----------------
__global__ void gemm_edge_fused(const float* __restrict__ src, const int* __restrict__ es,
                                const int* __restrict__ ed, const float* __restrict__ W1,
                                const float* __restrict__ b1, const float* __restrict__ w2,
                                float* __restrict__ a_pre) {
    __shared__ float As[TK][TM + 4];
    __shared__ float Bs[TK][TN + 4];
    __shared__ float red[TM][17];
    int tid = threadIdx.x;
    int tx = tid & 15, ty = tid >> 4;
    int e0 = blockIdx.y * TM, col0 = blockIdx.x * TN;
    int lr = tid >> 2, lc4 = (tid & 3) * 4;
    int ea = es[e0 + lr], eb = ed[e0 + lr];
    const float* ra = src + (size_t)ea * 256;
    const float* rb = src + (size_t)eb * 256;
    float acc[4][4] = {};
    for (int k0 = 0; k0 < 512; k0 += TK) {
        {
            int k = k0 + lc4;
            float4 va, vb;
            if (k < 256) {
                va = *(const float4*)(ra + k); vb = *(const float4*)(rb + k);
                As[lc4 + 0][lr] = 0.5f * (va.x + vb.x);
                As[lc4 + 1][lr] = 0.5f * (va.y + vb.y);
                As[lc4 + 2][lr] = 0.5f * (va.z + vb.z);
                As[lc4 + 3][lr] = 0.5f * (va.w + vb.w);
            } else {
                va = *(const float4*)(ra + k - 256); vb = *(const float4*)(rb + k - 256);
                As[lc4 + 0][lr] = fmaxf(va.x, vb.x);
                As[lc4 + 1][lr] = fmaxf(va.y, vb.y);
                As[lc4 + 2][lr] = fmaxf(va.z, vb.z);
                As[lc4 + 3][lr] = fmaxf(va.w, vb.w);
            }
        }
        {
            int n = tid & 63, kk0 = tid >> 6;
#pragma unroll
            for (int p = 0; p < 4; p++) {
                int kk = kk0 + p * 4;
                Bs[kk][n] = W1[(size_t)(k0 + kk) * 256 + col0 + n];
            }
        }
        __syncthreads();
#pragma unroll
        for (int kk = 0; kk < TK; kk++) {
            float4 a = *(const float4*)&As[kk][ty * 4];
            float4 b = *(const float4*)&Bs[kk][tx * 4];
            float av[4] = {a.x, a.y, a.z, a.w};
            float bv[4] = {b.x, b.y, b.z, b.w};
#pragma unroll
            for (int i = 0; i < 4; i++)
#pragma unroll
                for (int j = 0; j < 4; j++) acc[i][j] += av[i] * bv[j];
        }
        __syncthreads();
    }
    float part[4];
#pragma unroll
    for (int i = 0; i < 4; i++) {
        float s = 0.f;
#pragma unroll
        for (int j = 0; j < 4; j++) {
            int c = col0 + tx * 4 + j;
            float h = tanhf(acc[i][j] + b1[c]);
            s += h * w2[c];
        }
        part[i] = s;
    }
#pragma unroll
    for (int i = 0; i < 4; i++) red[ty * 4 + i][tx] = part[i];
    __syncthreads();
    if (tid < 64) {
        float s = 0.f;
        for (int q = 0; q < 16; q++) s += red[tid][q];
        atomicAdd(&a_pre[e0 + tid], s);
    }
}

// ---------------- edge bilinear: sigmoid(g[es].emb2[ed] + sum(bias_lin)) ----------------
__global__ void k_edge_sim(const float* g, const float* emb2, const int* __restrict__ es,
                           const int* __restrict__ ed, const float* __restrict__ sumb,
                           float* __restrict__ mlsc) {
    int tid = threadIdx.x;
    int lane = tid & 63, w = tid >> 6;
    int e = blockIdx.x * 4 + w;
    if (e >= E_) return;
    int a = es[e], b = ed[e];
    const float4* g4 = (const float4*)g;
    const float4* m4 = (const float4*)emb2;
    float4 x = g4[(size_t)a * 64 + lane];
    float4 y = m4[(size_t)b * 64 + lane];
    float d = x.x * y.x + x.y * y.y + x.z * y.z + x.w * y.w;
    for (int o = 32; o > 0; o >>= 1) d += __shfl_xor(d, o);
    if (lane == 0) mlsc[e] = 1.f / (1.f + expf(-(d + sumb[0])));
}

// ---------------- final ensemble ----------------
__global__ void k_final(const float* __restrict__ apml, const float* __restrict__ apms,
                        const float* __restrict__ mlsc, const float* __restrict__ mstr,
                        const float* __restrict__ pxtr, const int* __restrict__ index,
                        const float* __restrict__ mlb2, const float* __restrict__ msb2,
                        float* __restrict__ out) {
    int e = blockIdx.x * 256 + threadIdx.x;
    if (e >= E_) return;
    float aml = tanhf(apml[e] + mlb2[0]);
    float ams = tanhf(apms[e] + msb2[0]);
    float apx = PROXW;
    float m = fmaxf(aml, fmaxf(ams, apx));
    float wml = expf(aml - m), wms = expf(ams - m), wpx = expf(apx - m);
    float inv = 1.f / (wml + wms + wpx);
    int idx = index[e];
    float v = (mlsc[e] * wml + mstr[idx] * wms + pxtr[idx] * wpx) * inv;
    out[e] = fminf(fmaxf(v, 0.f), 1.f);
}

__global__ void k_sentinel(float* out, int n) {
    int i = blockIdx.x * 256 + threadIdx.x;
    if (i < n) out[i] = -12345.0f;
}

// ---------------- launch ----------------
extern "C" void kernel_launch(void* const* d_in, const int* in_sizes, int n_in,
                              void* d_out, int out_size, void* d_ws, size_t ws_size,
                              hipStream_t stream) {
    const float* x     = (const float*)d_in[0];
    const int*   mp    = (const int*)d_in[1];
    const int*   edges = (const int*)d_in[2];
    const int*   index = (const int*)d_in[3];
    const float* p0    = (const float*)d_in[4];
    const float* p1    = (const float*)d_in[5];
    const float* p2    = (const float*)d_in[6];
    const float* gc1W  = (const float*)d_in[7];
    const float* gc1b  = (const float*)d_in[8];
    const float* gc2W  = (const float*)d_in[9];
    const float* gc2b  = (const float*)d_in[10];
    const float* linW  = (const float*)d_in[11];
    const float* linb  = (const float*)d_in[12];
    const float* wlin  = (const float*)d_in[13];
    const float* blin  = (const float*)d_in[14];
    const float* wq    = (const float*)d_in[15];
    const float* wk    = (const float*)d_in[16];
    const float* wv    = (const float*)d_in[17];
    const float* mlw1  = (const float*)d_in[18];
    const float* mlb1  = (const float*)d_in[19];
    const float* mlw2  = (const float*)d_in[20];
    const float* mlb2  = (const float*)d_in[21];
    const float* msw1  = (const float*)d_in[22];
    const float* msb1  = (const float*)d_in[23];
    const float* msw2  = (const float*)d_in[24];
    const float* msb2  = (const float*)d_in[25];
    const float* msdrW = (const float*)d_in[26];
    const float* msdrb = (const float*)d_in[27];
    const float* logits = (const float*)d_in[28];
    const float* mstr  = (const float*)d_in[29];
    const float* pxtr  = (const float*)d_in[30];
    float* out = (float*)d_out;

    const int* src_mp = mp;
    const int* dst_mp = mp + EMP_;
    const int* es = edges;
    const int* ed = edges + E_;

    // workspace layout
    char* ws = (char*)d_ws;
    size_t off = 0;
    auto alloc = [&](size_t bytes) -> char* {
        off = (off + 255) & ~(size_t)255;
        char* p = ws + off;
        off += bytes;
        return p;
    };
    float* B1   = (float*)alloc((size_t)Nn_ * H_ * 4);
    float* B2   = (float*)alloc((size_t)Nn_ * H_ * 4);
    float* B3   = (float*)alloc((size_t)Nn_ * H_ * 4);
    int*   cnt  = (int*)alloc((size_t)Nn_ * 4);
    int*   rowp = (int*)alloc((size_t)(Nn_ + 1) * 4);
    int*   fill = (int*)alloc((size_t)Nn_ * 4);
    int*   csr  = (int*)alloc((size_t)EMP_ * 4);
    float* dinv = (float*)alloc((size_t)Nn_ * 4);
    int*   bsum = (int*)alloc(512 * 4);
    float* Mqk  = (float*)alloc(65536 * 4);
    float* W2w  = (float*)alloc(65536 * 4);
    float* symw = (float*)alloc(65536 * 4);
    float* apml = (float*)alloc((size_t)E_ * 4);
    float* apms = (float*)alloc((size_t)E_ * 4);
    float* mlsc = (float*)alloc((size_t)E_ * 4);
    float* sumb = (float*)alloc(256);

    if (off > ws_size) {
        k_sentinel<<<(E_ + 255) / 256, 256, 0, stream>>>(out, E_);
        return;
    }

    // zero what we accumulate into
    hipMemsetAsync(cnt, 0, (size_t)Nn_ * 4, stream);
    hipMemsetAsync(fill, 0, (size_t)Nn_ * 4, stream);
    hipMemsetAsync(apml, 0, (size_t)E_ * 4, stream);
    hipMemsetAsync(apms, 0, (size_t)E_ * 4, stream);

    const int NB = (Nn_ + 255) / 256;           // 469
    const int EB = (EMP_ + 255) / 256;          // 3907

    // CSR
    k_count<<<EB, 256, 0, stream>>>(dst_mp, cnt, EMP_);
    k_block_reduce<<<NB, 256, 0, stream>>>(cnt, bsum, Nn_);
    k_scan_bsum<<<1, 64, 0, stream>>>(bsum, NB);
    k_scan_final<<<NB, 256, 0, stream>>>(cnt, bsum, rowp, Nn_, EMP_);
    k_fill<<<EB, 256, 0, stream>>>(src_mp, dst_mp, rowp, fill, csr, EMP_);
    k_dinv<<<NB, 256, 0, stream>>>(cnt, dinv, Nn_);

    dim3 gFull(4, (Nn_ + TM - 1) / TM);   // 4 x 1875
    dim3 gSmall(4, 4);

    // GCN layer 1: xw1 = x @ gc1W -> B1 ; h = agg -> B2
    gemm_tiled<false, false, false, false><<<gFull, 256, 0, stream>>>(x, gc1W, nullptr, B1, Nn_, 256, 256);
    k_aggregate<<<Nn_, 256, 0, stream>>>(B1, rowp, csr, dinv, gc1b, B2);
    // GCN layer 2: xw2 = h @ gc2W -> B1 ; emb = agg -> B2
    gemm_tiled<false, false, false, false><<<gFull, 256, 0, stream>>>(B2, gc2W, nullptr, B1, Nn_, 256, 256);
    k_aggregate<<<Nn_, 256, 0, stream>>>(B1, rowp, csr, dinv, gc2b, B2);
    // B2 = emb from here on (until emb2 done)

    // small precomputes
    gemm_tiled<true, false, false, false><<<gSmall, 256, 0, stream>>>(wq, wk, nullptr, Mqk, 256, 256, 256);
    gemm_tiled<false, false, false, false><<<gSmall, 256, 0, stream>>>(wv, linW + 256 * 256, nullptr, W2w, 256, 256, 256);
    k_sym<<<256, 256, 0, stream>>>(wlin, symw);
    k_sumb<<<1, 256, 0, stream>>>(blin, sumb);

    // attention: t = emb @ Mqk (rows < 100000) -> B1 ; u (in-place over t) -> B1
    dim3 gT(4, (P2_ + TM - 1) / TM);
    gemm_tiled<false, false, false, false><<<gT, 256, 0, stream>>>(B2, Mqk, nullptr, B1, P2_, 256, 256);
    k_attn_u<<<Nn_ / 4, 256, 0, stream>>>(B2, B1, p0, p1, p2, B1);

    // emb2 = tanh(emb @ L_top + u @ (wv@L_bot) + linb) -> B3
    gemm_tiled<false, false, false, false><<<gFull, 256, 0, stream>>>(B2, linW, nullptr, B3, Nn_, 256, 256);
    gemm_tiled<false, true, true, true><<<gFull, 256, 0, stream>>>(B1, W2w, linb, B3, Nn_, 256, 256);

    // g = emb2 @ sym -> B1 ; r = tanh(logits @ msdrW + msdrb) -> B2
    gemm_tiled<false, false, false, false><<<gFull, 256, 0, stream>>>(B3, symw, nullptr, B1, Nn_, 256, 256);
    gemm_tiled<false, false, true, true><<<gFull, 256, 0, stream>>>(logits, msdrW, msdrb, B2, Nn_, 64, 256);

    // edge MLPs (fused layer2 via atomics)
    dim3 gE(4, E_ / TM);   // 4 x 3125
    gemm_edge_fused<<<gE, 256, 0, stream>>>(B3, es, ed, mlw1, mlb1, mlw2, apml);
    gemm_edge_fused<<<gE, 256, 0, stream>>>(B2, es, ed, msw1, msb1, msw2, apms);

    // bilinear sims
    k_edge_sim<<<E_ / 4, 256, 0, stream>>>(B1, B3, es, ed, sumb, mlsc);

    // final ensemble
    k_final<<<(E_ + 255) / 256, 256, 0, stream>>>(apml, apms, mlsc, mstr, pxtr, index, mlb2, msb2, out);
}

// Round 2
// 1354.191 us; speedup vs baseline: 2.9981x; 2.9981x over previous
//
#include <hip/hip_runtime.h>
#include <hip/hip_bf16.h>

// ---------------- constants ----------------
#define Nn_   120000
#define F_    256
#define H_    256
#define L_    64
#define EMP_  1000000
#define E_    200000
#define P0_   60000
#define P1_   80000
#define P2_   100000
#define PROXW 0.3f

typedef __attribute__((ext_vector_type(8))) short bf16x8;
typedef __attribute__((ext_vector_type(4))) float f32x4;

__device__ inline float bf2f(unsigned short u) {
    union { unsigned int i; float f; } x; x.i = ((unsigned int)u) << 16; return x.f;
}
__device__ inline unsigned short f2bf(float f) {
    union { float f; unsigned int i; } x; x.f = f;
    unsigned int r = x.i + 0x7fffu + ((x.i >> 16) & 1u);
    return (unsigned short)(r >> 16);
}
__device__ inline int lds_off(int row, int s) {
    return row * 64 + ((s ^ ((row >> 1) & 3)) << 4);
}
__device__ inline void gload_lds16(const void* g, void* l) {
    __builtin_amdgcn_global_load_lds((const __attribute__((address_space(1))) void*)g,
                                     (__attribute__((address_space(3))) void*)l, 16, 0, 0);
}

// ---------------- CSR build ----------------
__global__ void k_count(const int* __restrict__ dst, int* __restrict__ cnt, int n) {
    int e = blockIdx.x * 256 + threadIdx.x;
    if (e < n) atomicAdd(&cnt[dst[e]], 1);
}
__global__ void k_block_reduce(const int* __restrict__ cnt, int* __restrict__ bsum, int n) {
    __shared__ int s[256];
    int i = blockIdx.x * 256 + threadIdx.x;
    s[threadIdx.x] = (i < n) ? cnt[i] : 0;
    __syncthreads();
    for (int o = 128; o > 0; o >>= 1) {
        if (threadIdx.x < o) s[threadIdx.x] += s[threadIdx.x + o];
        __syncthreads();
    }
    if (threadIdx.x == 0) bsum[blockIdx.x] = s[0];
}
__global__ void k_scan_bsum(int* bsum, int nb) {
    if (threadIdx.x == 0 && blockIdx.x == 0) {
        int acc = 0;
        for (int i = 0; i < nb; i++) { int v = bsum[i]; bsum[i] = acc; acc += v; }
    }
}
__global__ void k_scan_final(const int* __restrict__ cnt, const int* __restrict__ bsum,
                             int* __restrict__ rowp, int n, int etot) {
    __shared__ int s[256];
    int tid = threadIdx.x;
    int i = blockIdx.x * 256 + tid;
    int v = (i < n) ? cnt[i] : 0;
    s[tid] = v;
    __syncthreads();
    for (int o = 1; o < 256; o <<= 1) {
        int t = 0;
        if (tid >= o) t = s[tid - o];
        __syncthreads();
        s[tid] += t;
        __syncthreads();
    }
    if (i < n) rowp[i] = bsum[blockIdx.x] + s[tid] - v;
    if (i == 0 && blockIdx.x == 0) rowp[n] = etot;
}
__global__ void k_fill(const int* __restrict__ src, const int* __restrict__ dst,
                       const int* __restrict__ rowp, int* __restrict__ fill,
                       int* __restrict__ csr, int n) {
    int e = blockIdx.x * 256 + threadIdx.x;
    if (e < n) {
        int d = dst[e];
        int p = atomicAdd(&fill[d], 1);
        csr[rowp[d] + p] = src[e];
    }
}
__global__ void k_dinv(const int* __restrict__ cnt, float* __restrict__ dinv, int n) {
    int i = blockIdx.x * 256 + threadIdx.x;
    if (i < n) dinv[i] = rsqrtf((float)cnt[i] + 1.0f);
}

// ---------------- small f32 tiled GEMM (for 256^3 precomputes only) ----------------
#define TM 64
#define TN 64
#define TK 16
template <bool TRANSB>
__global__ void gemm_tiled(const float* __restrict__ A, const float* __restrict__ B,
                           float* __restrict__ C, int M, int K, int N) {
    __shared__ float As[TK][TM + 4];
    __shared__ float Bs[TK][TN + 4];
    int tid = threadIdx.x;
    int tx = tid & 15, ty = tid >> 4;
    int row0 = blockIdx.y * TM, col0 = blockIdx.x * TN;
    int lr = tid >> 2, lc4 = (tid & 3) * 4;
    float acc[4][4] = {};
    for (int k0 = 0; k0 < K; k0 += TK) {
        {
            int gr = row0 + lr;
            float4 v = make_float4(0.f, 0.f, 0.f, 0.f);
            if (gr < M) v = *(const float4*)(A + (size_t)gr * K + k0 + lc4);
            As[lc4 + 0][lr] = v.x; As[lc4 + 1][lr] = v.y;
            As[lc4 + 2][lr] = v.z; As[lc4 + 3][lr] = v.w;
        }
        {
            int n = tid & 63, kk0 = tid >> 6;
#pragma unroll
            for (int p = 0; p < 4; p++) {
                int kk = kk0 + p * 4;
                if (TRANSB) Bs[kk][n] = B[(size_t)(col0 + n) * K + k0 + kk];
                else        Bs[kk][n] = B[(size_t)(k0 + kk) * N + col0 + n];
            }
        }
        __syncthreads();
#pragma unroll
        for (int kk = 0; kk < TK; kk++) {
            float4 a = *(const float4*)&As[kk][ty * 4];
            float4 b = *(const float4*)&Bs[kk][tx * 4];
            float av[4] = {a.x, a.y, a.z, a.w};
            float bv[4] = {b.x, b.y, b.z, b.w};
#pragma unroll
            for (int i = 0; i < 4; i++)
#pragma unroll
                for (int j = 0; j < 4; j++) acc[i][j] += av[i] * bv[j];
        }
        __syncthreads();
    }
#pragma unroll
    for (int i = 0; i < 4; i++) {
        int r = row0 + ty * 4 + i;
        if (r >= M) continue;
#pragma unroll
        for (int j = 0; j < 4; j++) C[(size_t)r * N + col0 + tx * 4 + j] = acc[i][j];
    }
}

// ---------------- conversions / transposes ----------------
__global__ void k_cvt(const float* __restrict__ in, unsigned short* __restrict__ out, int n4) {
    int i = blockIdx.x * 256 + threadIdx.x;
    if (i >= n4) return;
    float4 v = ((const float4*)in)[i];
    ushort4 o;
    o.x = f2bf(v.x); o.y = f2bf(v.y); o.z = f2bf(v.z); o.w = f2bf(v.w);
    ((ushort4*)out)[i] = o;
}
// Wt[c][r] = bf(W[r][c]); grid = C blocks
__global__ void k_transpose_cvt(const float* __restrict__ W, unsigned short* __restrict__ Wt,
                                int R, int C) {
    int c = blockIdx.x;
    for (int r = threadIdx.x; r < R; r += 256)
        Wt[(size_t)c * R + r] = f2bf(W[(size_t)r * C + c]);
}
__global__ void k_sym_cvt(const float* __restrict__ W, unsigned short* __restrict__ symb) {
    int r = blockIdx.x, c = threadIdx.x;
    symb[r * 256 + c] = f2bf(0.5f * (W[r * 256 + c] + W[c * 256 + r]));
}
// Bt512[n][k] = k<256 ? linW[k][n] : W2w[k-256][n]
__global__ void k_bt512(const float* __restrict__ linW, const float* __restrict__ W2w,
                        unsigned short* __restrict__ Bt) {
    int idx = blockIdx.x * 256 + threadIdx.x;
    int n = idx >> 9, k = idx & 511;
    float v = (k < 256) ? linW[(size_t)k * 256 + n] : W2w[(size_t)(k - 256) * 256 + n];
    Bt[idx] = f2bf(v);
}
__global__ void k_sumb(const float* __restrict__ b, float* __restrict__ out) {
    __shared__ float s[256];
    int tid = threadIdx.x;
    s[tid] = b[tid];
    __syncthreads();
    for (int o = 128; o > 0; o >>= 1) {
        if (tid < o) s[tid] += s[tid + o];
        __syncthreads();
    }
    if (tid == 0) out[0] = s[0];
}

// ---------------- GCN aggregation, bf16 in/out, f32 accum ----------------
__global__ void k_agg_bf(const unsigned short* __restrict__ xw, const int* __restrict__ rowp,
                         const int* __restrict__ csr, const float* __restrict__ dinv,
                         const float* __restrict__ bias, unsigned short* __restrict__ out) {
    int v = blockIdx.x;
    int j = threadIdx.x;  // 128 threads, 2 cols each
    const unsigned int* x32 = (const unsigned int*)xw;
    float a0 = 0.f, a1 = 0.f;
    int beg = rowp[v], end = rowp[v + 1];
    for (int p = beg; p < end; ++p) {
        int s = csr[p];
        float d = dinv[s];
        unsigned int u = x32[(size_t)s * 128 + j];
        a0 += bf2f(u & 0xffff) * d;
        a1 += bf2f(u >> 16) * d;
    }
    float dv = dinv[v];
    unsigned int us = x32[(size_t)v * 128 + j];
    a0 = a0 * dv + bf2f(us & 0xffff) * dv * dv;
    a1 = a1 * dv + bf2f(us >> 16) * dv * dv;
    float t0 = tanhf(a0 + bias[2 * j]);
    float t1 = tanhf(a1 + bias[2 * j + 1]);
    ((unsigned int*)out)[(size_t)v * 128 + j] = ((unsigned int)f2bf(t1) << 16) | f2bf(t0);
}

// ---------------- MFMA GEMM: C[M x 256] = op(A[M x K] @ Bt^T), A dual-segment ----------------
template <bool BIAS, bool TANH>
__global__ __launch_bounds__(256)
void mfma_gemm(const unsigned short* __restrict__ A0, const unsigned short* __restrict__ A1,
               int Ksplit, int K, const unsigned short* __restrict__ Bt,
               const float* __restrict__ bias, unsigned short* __restrict__ Cb, int M) {
    __shared__ char lds[16384];
    int tid = threadIdx.x, lane = tid & 63, w = tid >> 6;
    int row0 = blockIdx.y * 128, col0 = blockIdx.x * 128;
    int wr = w >> 1, wc = w & 1;
    f32x4 acc[4][4] = {};
    int nk = K >> 5;
    for (int ks = 0; ks < nk; ++ks) {
        int k0 = ks << 5;
        __syncthreads();
        #pragma unroll
        for (int j = 0; j < 4; ++j) {
            int ins = w + (j << 2);
            int lrow = ((ins & 7) << 4) + (lane >> 2);
            int p = lane & 3;
            int slog = p ^ ((lrow >> 1) & 3);
            char* ldst = lds + ((ins & 7) << 10) + ((ins >= 8) ? 8192 : 0);
            const unsigned short* src;
            if (ins < 8) {
                int grow = row0 + lrow;
                if (grow >= M) grow = M - 1;
                const unsigned short* Asrc; int kk, pitch;
                if (k0 < Ksplit) { Asrc = A0; kk = k0; pitch = Ksplit; }
                else             { Asrc = A1; kk = k0 - Ksplit; pitch = K - Ksplit; }
                src = Asrc + (size_t)grow * pitch + kk + (slog << 3);
            } else {
                int grow = col0 + lrow;
                src = Bt + (size_t)grow * K + k0 + (slog << 3);
            }
            gload_lds16(src, ldst);
        }
        asm volatile("s_waitcnt vmcnt(0)" ::: "memory");
        __syncthreads();
        int s = lane >> 4, r16 = lane & 15;
        bf16x8 a[4], b[4];
        #pragma unroll
        for (int m = 0; m < 4; ++m) a[m] = *(const bf16x8*)(lds + lds_off(wr * 64 + m * 16 + r16, s));
        #pragma unroll
        for (int n = 0; n < 4; ++n) b[n] = *(const bf16x8*)(lds + 8192 + lds_off(wc * 64 + n * 16 + r16, s));
        #pragma unroll
        for (int m = 0; m < 4; ++m)
            #pragma unroll
            for (int n = 0; n < 4; ++n)
                acc[m][n] = __builtin_amdgcn_mfma_f32_16x16x32_bf16(a[m], b[n], acc[m][n], 0, 0, 0);
    }
    int q = lane >> 4, r16 = lane & 15;
    float bv[4];
    #pragma unroll
    for (int n = 0; n < 4; ++n) bv[n] = BIAS ? bias[col0 + wc * 64 + n * 16 + r16] : 0.f;
    #pragma unroll
    for (int m = 0; m < 4; ++m) {
        #pragma unroll
        for (int i = 0; i < 4; ++i) {
            int row = row0 + wr * 64 + m * 16 + q * 4 + i;
            if (row >= M) continue;
            #pragma unroll
            for (int n = 0; n < 4; ++n) {
                int col = col0 + wc * 64 + n * 16 + r16;
                float v = acc[m][n][i];
                if (BIAS) v += bv[n];
                if (TANH) v = tanhf(v);
                Cb[(size_t)row * 256 + col] = f2bf(v);
            }
        }
    }
}

// ---------------- attention u (bf16 emb/t/u, f32 prevs) ----------------
__global__ void k_attn_u_bf(const unsigned short* __restrict__ emb, const unsigned short* __restrict__ t,
                            const float* __restrict__ p0, const float* __restrict__ p1,
                            const float* __restrict__ p2, unsigned short* __restrict__ u) {
    int tid = threadIdx.x;
    int lane = tid & 63, w = tid >> 6;
    int n = blockIdx.x * 4 + w;
    size_t base = (size_t)n * 64 + lane;
    const ushort4* e4 = (const ushort4*)emb;
    ushort4* u4 = (ushort4*)u;
    if (n >= P2_) { u4[base] = e4[base]; return; }
    const float* pf[3];
    int S;
    if (n < P0_)      { pf[0] = p0; pf[1] = p1; pf[2] = p2; S = 4; }
    else if (n < P1_) { pf[0] = p1; pf[1] = p2; S = 3; }
    else              { pf[0] = p2; S = 2; }
    ushort4 tb = ((const ushort4*)t)[base];
    float4 tv = make_float4(bf2f(tb.x), bf2f(tb.y), bf2f(tb.z), bf2f(tb.w));
    float4 sv[4];
    for (int s = 0; s < S - 1; s++) sv[s] = ((const float4*)pf[s])[base];
    {
        ushort4 eb = e4[base];
        sv[S - 1] = make_float4(bf2f(eb.x), bf2f(eb.y), bf2f(eb.z), bf2f(eb.w));
    }
    float lg[4];
    for (int s = 0; s < S; s++) {
        float d = tv.x * sv[s].x + tv.y * sv[s].y + tv.z * sv[s].z + tv.w * sv[s].w;
        for (int o = 32; o > 0; o >>= 1) d += __shfl_xor(d, o);
        lg[s] = d * 0.0625f;
    }
    float m = lg[0];
    for (int s = 1; s < S; s++) m = fmaxf(m, lg[s]);
    float wgt[4], den = 0.f;
    for (int s = 0; s < S; s++) { wgt[s] = expf(lg[s] - m); den += wgt[s]; }
    float inv = 1.f / den;
    float4 o = make_float4(0.f, 0.f, 0.f, 0.f);
    for (int s = 0; s < S; s++) {
        float ws = wgt[s] * inv;
        o.x += ws * sv[s].x; o.y += ws * sv[s].y; o.z += ws * sv[s].z; o.w += ws * sv[s].w;
    }
    ushort4 ov;
    ov.x = f2bf(o.x); ov.y = f2bf(o.y); ov.z = f2bf(o.z); ov.w = f2bf(o.w);
    u4[base] = ov;
}

// ---------------- fused edge MLP via MFMA ----------------
__device__ inline void unpk8(uint4 u, float* o) {
    o[0] = bf2f(u.x & 0xffff); o[1] = bf2f(u.x >> 16);
    o[2] = bf2f(u.y & 0xffff); o[3] = bf2f(u.y >> 16);
    o[4] = bf2f(u.z & 0xffff); o[5] = bf2f(u.z >> 16);
    o[6] = bf2f(u.w & 0xffff); o[7] = bf2f(u.w >> 16);
}
__global__ __launch_bounds__(256)
void mfma_edge(const unsigned short* __restrict__ srcemb, const int* __restrict__ es,
               const int* __restrict__ ed, const unsigned short* __restrict__ W1t,
               const float* __restrict__ b1, const float* __restrict__ w2,
               float* __restrict__ a_pre) {
    __shared__ char lds[4096 + 16384];
    __shared__ float red[64];
    int tid = threadIdx.x, lane = tid & 63, w = tid >> 6;
    int e0 = blockIdx.x * 64;
    int arow = tid >> 2, p = tid & 3;
    const unsigned short* ra = srcemb + (size_t)es[e0 + arow] * 256;
    const unsigned short* rb = srcemb + (size_t)ed[e0 + arow] * 256;
    int slog = p ^ ((arow >> 1) & 3);
    if (tid < 64) red[tid] = 0.f;
    f32x4 acc[4][4] = {};
    for (int ks = 0; ks < 16; ++ks) {
        int k0 = ks << 5;
        int klog = k0 + (slog << 3);
        __syncthreads();
        // A reg-stage (gather + meanmax + cvt + swizzled ds_write)
        {
            float fa[8], fb[8];
            int kk = (klog < 256) ? klog : (klog - 256);
            uint4 ua = *(const uint4*)(ra + kk);
            uint4 ub = *(const uint4*)(rb + kk);
            unpk8(ua, fa); unpk8(ub, fb);
            bf16x8 v;
            if (klog < 256) {
                #pragma unroll
                for (int i = 0; i < 8; i++) v[i] = (short)f2bf(0.5f * (fa[i] + fb[i]));
            } else {
                #pragma unroll
                for (int i = 0; i < 8; i++) v[i] = (short)f2bf(fmaxf(fa[i], fb[i]));
            }
            *(bf16x8*)(lds + arow * 64 + (p << 4)) = v;
        }
        // B stage: Bt[256][512] slice, 16 instrs across 4 waves
        #pragma unroll
        for (int j = 0; j < 4; ++j) {
            int ins = (j << 2) + w;
            int lrow = (ins << 4) + (lane >> 2);
            int pp = lane & 3;
            int sl = pp ^ ((lrow >> 1) & 3);
            const unsigned short* src = W1t + (size_t)lrow * 512 + k0 + (sl << 3);
            gload_lds16(src, lds + 4096 + (ins << 10));
        }
        asm volatile("s_waitcnt vmcnt(0)" ::: "memory");
        __syncthreads();
        int s = lane >> 4, r16 = lane & 15;
        bf16x8 a[4], b[4];
        #pragma unroll
        for (int m = 0; m < 4; ++m) a[m] = *(const bf16x8*)(lds + lds_off(m * 16 + r16, s));
        #pragma unroll
        for (int n = 0; n < 4; ++n) b[n] = *(const bf16x8*)(lds + 4096 + lds_off(w * 64 + n * 16 + r16, s));
        #pragma unroll
        for (int m = 0; m < 4; ++m)
            #pragma unroll
            for (int n = 0; n < 4; ++n)
                acc[m][n] = __builtin_amdgcn_mfma_f32_16x16x32_bf16(a[m], b[n], acc[m][n], 0, 0, 0);
    }
    // epilogue: s[row] += sum_c tanh(h+b1)*w2 over this wave's 64 cols
    int q = lane >> 4, r16 = lane & 15;
    float b1c[4], w2c[4];
    #pragma unroll
    for (int n = 0; n < 4; ++n) {
        int c = w * 64 + n * 16 + r16;
        b1c[n] = b1[c]; w2c[n] = w2[c];
    }
    #pragma unroll
    for (int m = 0; m < 4; ++m) {
        #pragma unroll
        for (int i = 0; i < 4; ++i) {
            int row = m * 16 + q * 4 + i;
            float ps = 0.f;
            #pragma unroll
            for (int n = 0; n < 4; ++n) ps += tanhf(acc[m][n][i] + b1c[n]) * w2c[n];
            ps += __shfl_xor(ps, 1);
            ps += __shfl_xor(ps, 2);
            ps += __shfl_xor(ps, 4);
            ps += __shfl_xor(ps, 8);
            if (r16 == 0) atomicAdd(&red[row], ps);
        }
    }
    __syncthreads();
    if (tid < 64) a_pre[e0 + tid] = red[tid];
}

// ---------------- edge bilinear (bf16 g, emb2) ----------------
__global__ void k_edge_sim(const unsigned short* __restrict__ g, const unsigned short* __restrict__ emb2,
                           const int* __restrict__ es, const int* __restrict__ ed,
                           const float* __restrict__ sumb, float* __restrict__ mlsc) {
    int tid = threadIdx.x;
    int lane = tid & 63, w = tid >> 6;
    int e = blockIdx.x * 4 + w;
    int a = es[e], b = ed[e];
    ushort4 gx = ((const ushort4*)g)[(size_t)a * 64 + lane];
    ushort4 ey = ((const ushort4*)emb2)[(size_t)b * 64 + lane];
    float d = bf2f(gx.x) * bf2f(ey.x) + bf2f(gx.y) * bf2f(ey.y) +
              bf2f(gx.z) * bf2f(ey.z) + bf2f(gx.w) * bf2f(ey.w);
    for (int o = 32; o > 0; o >>= 1) d += __shfl_xor(d, o);
    if (lane == 0) mlsc[e] = 1.f / (1.f + expf(-(d + sumb[0])));
}

// ---------------- final ensemble ----------------
__global__ void k_final(const float* __restrict__ apml, const float* __restrict__ apms,
                        const float* __restrict__ mlsc, const float* __restrict__ mstr,
                        const float* __restrict__ pxtr, const int* __restrict__ index,
                        const float* __restrict__ mlb2, const float* __restrict__ msb2,
                        float* __restrict__ out) {
    int e = blockIdx.x * 256 + threadIdx.x;
    if (e >= E_) return;
    float aml = tanhf(apml[e] + mlb2[0]);
    float ams = tanhf(apms[e] + msb2[0]);
    float apx = PROXW;
    float m = fmaxf(aml, fmaxf(ams, apx));
    float wml = expf(aml - m), wms = expf(ams - m), wpx = expf(apx - m);
    float inv = 1.f / (wml + wms + wpx);
    int idx = index[e];
    float v = (mlsc[e] * wml + mstr[idx] * wms + pxtr[idx] * wpx) * inv;
    out[e] = fminf(fmaxf(v, 0.f), 1.f);
}

__global__ void k_sentinel(float* out, int n) {
    int i = blockIdx.x * 256 + threadIdx.x;
    if (i < n) out[i] = -12345.0f;
}

// ---------------- launch ----------------
extern "C" void kernel_launch(void* const* d_in, const int* in_sizes, int n_in,
                              void* d_out, int out_size, void* d_ws, size_t ws_size,
                              hipStream_t stream) {
    const float* x     = (const float*)d_in[0];
    const int*   mp    = (const int*)d_in[1];
    const int*   edges = (const int*)d_in[2];
    const int*   index = (const int*)d_in[3];
    const float* p0    = (const float*)d_in[4];
    const float* p1    = (const float*)d_in[5];
    const float* p2    = (const float*)d_in[6];
    const float* gc1W  = (const float*)d_in[7];
    const float* gc1b  = (const float*)d_in[8];
    const float* gc2W  = (const float*)d_in[9];
    const float* gc2b  = (const float*)d_in[10];
    const float* linW  = (const float*)d_in[11];
    const float* linb  = (const float*)d_in[12];
    const float* wlin  = (const float*)d_in[13];
    const float* blin  = (const float*)d_in[14];
    const float* wq    = (const float*)d_in[15];
    const float* wk    = (const float*)d_in[16];
    const float* wv    = (const float*)d_in[17];
    const float* mlw1  = (const float*)d_in[18];
    const float* mlb1  = (const float*)d_in[19];
    const float* mlw2  = (const float*)d_in[20];
    const float* mlb2  = (const float*)d_in[21];
    const float* msw1  = (const float*)d_in[22];
    const float* msb1  = (const float*)d_in[23];
    const float* msw2  = (const float*)d_in[24];
    const float* msb2  = (const float*)d_in[25];
    const float* msdrW = (const float*)d_in[26];
    const float* msdrb = (const float*)d_in[27];
    const float* logits = (const float*)d_in[28];
    const float* mstr  = (const float*)d_in[29];
    const float* pxtr  = (const float*)d_in[30];
    float* out = (float*)d_out;

    const int* src_mp = mp;
    const int* dst_mp = mp + EMP_;
    const int* es = edges;
    const int* ed = edges + E_;

    char* ws = (char*)d_ws;
    size_t off = 0;
    auto alloc = [&](size_t bytes) -> char* {
        off = (off + 255) & ~(size_t)255;
        char* r = ws + off;
        off += bytes;
        return r;
    };
    const size_t NODE_BF = (size_t)Nn_ * 256 * 2;  // 61.44 MB
    unsigned short* W0 = (unsigned short*)alloc(NODE_BF);  // xb -> gb
    unsigned short* W1 = (unsigned short*)alloc(NODE_BF);  // xw1/xw2 -> logitsb
    unsigned short* W2 = (unsigned short*)alloc(NODE_BF);  // hb -> rb
    unsigned short* W3 = (unsigned short*)alloc(NODE_BF);  // embb
    unsigned short* W4 = (unsigned short*)alloc(NODE_BF);  // tb/ub
    unsigned short* W5 = (unsigned short*)alloc(NODE_BF);  // emb2b
    int*   cnt  = (int*)alloc((size_t)Nn_ * 4);
    int*   rowp = (int*)alloc((size_t)(Nn_ + 1) * 4);
    int*   fill = (int*)alloc((size_t)Nn_ * 4);
    int*   csr  = (int*)alloc((size_t)EMP_ * 4);
    float* dinv = (float*)alloc((size_t)Nn_ * 4);
    int*   bsum = (int*)alloc(512 * 4);
    float* Mqk  = (float*)alloc(65536 * 4);
    float* W2wf = (float*)alloc(65536 * 4);
    unsigned short* gc1Wt = (unsigned short*)alloc(65536 * 2);
    unsigned short* gc2Wt = (unsigned short*)alloc(65536 * 2);
    unsigned short* MqkT  = (unsigned short*)alloc(65536 * 2);
    unsigned short* Bt512 = (unsigned short*)alloc(131072 * 2);
    unsigned short* symb  = (unsigned short*)alloc(65536 * 2);
    unsigned short* msdrWt = (unsigned short*)alloc(16384 * 2);
    unsigned short* mlw1t = (unsigned short*)alloc(131072 * 2);
    unsigned short* msw1t = (unsigned short*)alloc(131072 * 2);
    float* apml = (float*)alloc((size_t)E_ * 4);
    float* apms = (float*)alloc((size_t)E_ * 4);
    float* mlsc = (float*)alloc((size_t)E_ * 4);
    float* sumb = (float*)alloc(256);

    if (off > ws_size) {
        k_sentinel<<<(E_ + 255) / 256, 256, 0, stream>>>(out, E_);
        return;
    }

    hipMemsetAsync(cnt, 0, (size_t)Nn_ * 4, stream);
    hipMemsetAsync(fill, 0, (size_t)Nn_ * 4, stream);

    const int NB = (Nn_ + 255) / 256;
    const int EB = (EMP_ + 255) / 256;

    // input conversions + weight prep (independent of pipeline)
    k_cvt<<<30000, 256, 0, stream>>>(x, W0, Nn_ * 256 / 4);
    k_transpose_cvt<<<256, 256, 0, stream>>>(gc1W, gc1Wt, 256, 256);
    k_transpose_cvt<<<256, 256, 0, stream>>>(gc2W, gc2Wt, 256, 256);
    k_transpose_cvt<<<256, 256, 0, stream>>>(msdrW, msdrWt, 64, 256);
    k_transpose_cvt<<<256, 256, 0, stream>>>(mlw1, mlw1t, 512, 256);
    k_transpose_cvt<<<256, 256, 0, stream>>>(msw1, msw1t, 512, 256);
    k_sym_cvt<<<256, 256, 0, stream>>>(wlin, symb);
    k_sumb<<<1, 256, 0, stream>>>(blin, sumb);
    dim3 gSmall(4, 4);
    gemm_tiled<true><<<gSmall, 256, 0, stream>>>(wq, wk, Mqk, 256, 256, 256);
    gemm_tiled<false><<<gSmall, 256, 0, stream>>>(wv, linW + 256 * 256, W2wf, 256, 256, 256);
    k_transpose_cvt<<<256, 256, 0, stream>>>(Mqk, MqkT, 256, 256);
    k_bt512<<<512, 256, 0, stream>>>(linW, W2wf, Bt512);

    // CSR
    k_count<<<EB, 256, 0, stream>>>(dst_mp, cnt, EMP_);
    k_block_reduce<<<NB, 256, 0, stream>>>(cnt, bsum, Nn_);
    k_scan_bsum<<<1, 64, 0, stream>>>(bsum, NB);
    k_scan_final<<<NB, 256, 0, stream>>>(cnt, bsum, rowp, Nn_, EMP_);
    k_fill<<<EB, 256, 0, stream>>>(src_mp, dst_mp, rowp, fill, csr, EMP_);
    k_dinv<<<NB, 256, 0, stream>>>(cnt, dinv, Nn_);

    dim3 gFull(2, (Nn_ + 127) / 128);   // (2, 938)
    dim3 gT(2, (P2_ + 127) / 128);      // (2, 782)

    // GCN layer 1
    mfma_gemm<false, false><<<gFull, 256, 0, stream>>>(W0, W0, 256, 256, gc1Wt, nullptr, W1, Nn_);
    k_agg_bf<<<Nn_, 128, 0, stream>>>(W1, rowp, csr, dinv, gc1b, W2);
    // GCN layer 2
    mfma_gemm<false, false><<<gFull, 256, 0, stream>>>(W2, W2, 256, 256, gc2Wt, nullptr, W1, Nn_);
    k_agg_bf<<<Nn_, 128, 0, stream>>>(W1, rowp, csr, dinv, gc2b, W3);

    // attention: t = emb @ Mqk (rows < P2), then u in-place
    mfma_gemm<false, false><<<gT, 256, 0, stream>>>(W3, W3, 256, 256, MqkT, nullptr, W4, P2_);
    k_attn_u_bf<<<Nn_ / 4, 256, 0, stream>>>(W3, W4, p0, p1, p2, W4);

    // emb2 = tanh([emb|u] @ Bt512^T + linb)
    mfma_gemm<true, true><<<gFull, 256, 0, stream>>>(W3, W4, 256, 512, Bt512, linb, W5, Nn_);

    // g = emb2 @ sym
    mfma_gemm<false, false><<<gFull, 256, 0, stream>>>(W5, W5, 256, 256, symb, nullptr, W0, Nn_);

    // r = tanh(logits @ msdrW + msdrb)  (logits converted into W1, now free)
    k_cvt<<<7500, 256, 0, stream>>>(logits, W1, Nn_ * 64 / 4);
    mfma_gemm<true, true><<<gFull, 256, 0, stream>>>(W1, W1, 64, 64, msdrWt, msdrb, W2, Nn_);

    // edge MLPs
    mfma_edge<<<E_ / 64, 256, 0, stream>>>(W5, es, ed, mlw1t, mlb1, mlw2, apml);
    mfma_edge<<<E_ / 64, 256, 0, stream>>>(W2, es, ed, msw1t, msb1, msw2, apms);

    // bilinear sims
    k_edge_sim<<<E_ / 4, 256, 0, stream>>>(W0, W5, es, ed, sumb, mlsc);

    // final ensemble
    k_final<<<(E_ + 255) / 256, 256, 0, stream>>>(apml, apms, mlsc, mstr, pxtr, index, mlb2, msb2, out);
}

// Round 3
// 1273.864 us; speedup vs baseline: 3.1872x; 1.0631x over previous
//
#include <hip/hip_runtime.h>
#include <hip/hip_bf16.h>

// ---------------- constants ----------------
#define Nn_   120000
#define F_    256
#define H_    256
#define L_    64
#define EMP_  1000000
#define E_    200000
#define P0_   60000
#define P1_   80000
#define P2_   100000
#define PROXW 0.3f

typedef __attribute__((ext_vector_type(8))) short bf16x8;
typedef __attribute__((ext_vector_type(4))) float f32x4;

__device__ inline float bf2f(unsigned short u) {
    union { unsigned int i; float f; } x; x.i = ((unsigned int)u) << 16; return x.f;
}
__device__ inline unsigned short f2bf(float f) {
    union { float f; unsigned int i; } x; x.f = f;
    unsigned int r = x.i + 0x7fffu + ((x.i >> 16) & 1u);
    return (unsigned short)(r >> 16);
}
__device__ inline int lds_off(int row, int s) {
    return row * 64 + ((s ^ ((row >> 1) & 3)) << 4);
}
__device__ inline void gload_lds16(const void* g, void* l) {
    __builtin_amdgcn_global_load_lds((const __attribute__((address_space(1))) void*)g,
                                     (__attribute__((address_space(3))) void*)l, 16, 0, 0);
}
__device__ inline void unpk8(uint4 u, float* o) {
    o[0] = bf2f(u.x & 0xffff); o[1] = bf2f(u.x >> 16);
    o[2] = bf2f(u.y & 0xffff); o[3] = bf2f(u.y >> 16);
    o[4] = bf2f(u.z & 0xffff); o[5] = bf2f(u.z >> 16);
    o[6] = bf2f(u.w & 0xffff); o[7] = bf2f(u.w >> 16);
}

// ---------------- CSR build ----------------
__global__ void k_count(const int* __restrict__ dst, int* __restrict__ cnt, int n) {
    int e = blockIdx.x * 256 + threadIdx.x;
    if (e < n) atomicAdd(&cnt[dst[e]], 1);
}
__global__ void k_block_reduce(const int* __restrict__ cnt, int* __restrict__ bsum, int n) {
    __shared__ int s[256];
    int i = blockIdx.x * 256 + threadIdx.x;
    s[threadIdx.x] = (i < n) ? cnt[i] : 0;
    __syncthreads();
    for (int o = 128; o > 0; o >>= 1) {
        if (threadIdx.x < o) s[threadIdx.x] += s[threadIdx.x + o];
        __syncthreads();
    }
    if (threadIdx.x == 0) bsum[blockIdx.x] = s[0];
}
__global__ void k_scan_bsum(int* bsum, int nb) {
    if (threadIdx.x == 0 && blockIdx.x == 0) {
        int acc = 0;
        for (int i = 0; i < nb; i++) { int v = bsum[i]; bsum[i] = acc; acc += v; }
    }
}
__global__ void k_scan_final(const int* __restrict__ cnt, const int* __restrict__ bsum,
                             int* __restrict__ rowp, int n, int etot) {
    __shared__ int s[256];
    int tid = threadIdx.x;
    int i = blockIdx.x * 256 + tid;
    int v = (i < n) ? cnt[i] : 0;
    s[tid] = v;
    __syncthreads();
    for (int o = 1; o < 256; o <<= 1) {
        int t = 0;
        if (tid >= o) t = s[tid - o];
        __syncthreads();
        s[tid] += t;
        __syncthreads();
    }
    if (i < n) rowp[i] = bsum[blockIdx.x] + s[tid] - v;
    if (i == 0 && blockIdx.x == 0) rowp[n] = etot;
}
__global__ void k_fill(const int* __restrict__ src, const int* __restrict__ dst,
                       const int* __restrict__ rowp, int* __restrict__ fill,
                       int* __restrict__ csr, int n) {
    int e = blockIdx.x * 256 + threadIdx.x;
    if (e < n) {
        int d = dst[e];
        int p = atomicAdd(&fill[d], 1);
        csr[rowp[d] + p] = src[e];
    }
}
__global__ void k_dinv(const int* __restrict__ cnt, float* __restrict__ dinv, int n) {
    int i = blockIdx.x * 256 + threadIdx.x;
    if (i < n) dinv[i] = rsqrtf((float)cnt[i] + 1.0f);
}

// ---------------- small f32 tiled GEMM (for 256^3 precomputes only) ----------------
#define TM 64
#define TN 64
#define TK 16
template <bool TRANSB>
__global__ void gemm_tiled(const float* __restrict__ A, const float* __restrict__ B,
                           float* __restrict__ C, int M, int K, int N) {
    __shared__ float As[TK][TM + 4];
    __shared__ float Bs[TK][TN + 4];
    int tid = threadIdx.x;
    int tx = tid & 15, ty = tid >> 4;
    int row0 = blockIdx.y * TM, col0 = blockIdx.x * TN;
    int lr = tid >> 2, lc4 = (tid & 3) * 4;
    float acc[4][4] = {};
    for (int k0 = 0; k0 < K; k0 += TK) {
        {
            int gr = row0 + lr;
            float4 v = make_float4(0.f, 0.f, 0.f, 0.f);
            if (gr < M) v = *(const float4*)(A + (size_t)gr * K + k0 + lc4);
            As[lc4 + 0][lr] = v.x; As[lc4 + 1][lr] = v.y;
            As[lc4 + 2][lr] = v.z; As[lc4 + 3][lr] = v.w;
        }
        {
            int n = tid & 63, kk0 = tid >> 6;
#pragma unroll
            for (int p = 0; p < 4; p++) {
                int kk = kk0 + p * 4;
                if (TRANSB) Bs[kk][n] = B[(size_t)(col0 + n) * K + k0 + kk];
                else        Bs[kk][n] = B[(size_t)(k0 + kk) * N + col0 + n];
            }
        }
        __syncthreads();
#pragma unroll
        for (int kk = 0; kk < TK; kk++) {
            float4 a = *(const float4*)&As[kk][ty * 4];
            float4 b = *(const float4*)&Bs[kk][tx * 4];
            float av[4] = {a.x, a.y, a.z, a.w};
            float bv[4] = {b.x, b.y, b.z, b.w};
#pragma unroll
            for (int i = 0; i < 4; i++)
#pragma unroll
                for (int j = 0; j < 4; j++) acc[i][j] += av[i] * bv[j];
        }
        __syncthreads();
    }
#pragma unroll
    for (int i = 0; i < 4; i++) {
        int r = row0 + ty * 4 + i;
        if (r >= M) continue;
#pragma unroll
        for (int j = 0; j < 4; j++) C[(size_t)r * N + col0 + tx * 4 + j] = acc[i][j];
    }
}

// ---------------- conversions / transposes ----------------
__global__ void k_cvt(const float* __restrict__ in, unsigned short* __restrict__ out, int n4) {
    int i = blockIdx.x * 256 + threadIdx.x;
    if (i >= n4) return;
    float4 v = ((const float4*)in)[i];
    ushort4 o;
    o.x = f2bf(v.x); o.y = f2bf(v.y); o.z = f2bf(v.z); o.w = f2bf(v.w);
    ((ushort4*)out)[i] = o;
}
__global__ void k_transpose_cvt(const float* __restrict__ W, unsigned short* __restrict__ Wt,
                                int R, int C) {
    int c = blockIdx.x;
    for (int r = threadIdx.x; r < R; r += 256)
        Wt[(size_t)c * R + r] = f2bf(W[(size_t)r * C + c]);
}
__global__ void k_sym_cvt(const float* __restrict__ W, unsigned short* __restrict__ symb) {
    int r = blockIdx.x, c = threadIdx.x;
    symb[r * 256 + c] = f2bf(0.5f * (W[r * 256 + c] + W[c * 256 + r]));
}
__global__ void k_bt512(const float* __restrict__ linW, const float* __restrict__ W2w,
                        unsigned short* __restrict__ Bt) {
    int idx = blockIdx.x * 256 + threadIdx.x;
    int n = idx >> 9, k = idx & 511;
    float v = (k < 256) ? linW[(size_t)k * 256 + n] : W2w[(size_t)(k - 256) * 256 + n];
    Bt[idx] = f2bf(v);
}
__global__ void k_sumb(const float* __restrict__ b, float* __restrict__ out) {
    __shared__ float s[256];
    int tid = threadIdx.x;
    s[tid] = b[tid];
    __syncthreads();
    for (int o = 128; o > 0; o >>= 1) {
        if (tid < o) s[tid] += s[tid + o];
        __syncthreads();
    }
    if (tid == 0) out[0] = s[0];
}

// ---------------- GCN aggregation: one wave per node ----------------
__global__ __launch_bounds__(256)
void k_agg_bf(const unsigned short* __restrict__ xw, const int* __restrict__ rowp,
              const int* __restrict__ csr, const float* __restrict__ dinv,
              const float* __restrict__ bias, unsigned short* __restrict__ out) {
    int w = threadIdx.x >> 6, lane = threadIdx.x & 63;
    int v = blockIdx.x * 4 + w;
    if (v >= Nn_) return;
    const uint2* x64 = (const uint2*)xw;  // 4 bf16 per lane
    float a0 = 0.f, a1 = 0.f, a2 = 0.f, a3 = 0.f;
    int beg = rowp[v], end = rowp[v + 1];
    for (int p = beg; p < end; ++p) {
        int s = csr[p];
        float d = dinv[s];
        uint2 uu = x64[(size_t)s * 64 + lane];
        a0 += bf2f(uu.x & 0xffff) * d;
        a1 += bf2f(uu.x >> 16) * d;
        a2 += bf2f(uu.y & 0xffff) * d;
        a3 += bf2f(uu.y >> 16) * d;
    }
    float dv = dinv[v];
    uint2 us = x64[(size_t)v * 64 + lane];
    a0 = a0 * dv + bf2f(us.x & 0xffff) * dv * dv;
    a1 = a1 * dv + bf2f(us.x >> 16) * dv * dv;
    a2 = a2 * dv + bf2f(us.y & 0xffff) * dv * dv;
    a3 = a3 * dv + bf2f(us.y >> 16) * dv * dv;
    int c0 = lane * 4;
    uint2 ov;
    ov.x = (unsigned int)f2bf(tanhf(a0 + bias[c0])) |
           ((unsigned int)f2bf(tanhf(a1 + bias[c0 + 1])) << 16);
    ov.y = (unsigned int)f2bf(tanhf(a2 + bias[c0 + 2])) |
           ((unsigned int)f2bf(tanhf(a3 + bias[c0 + 3])) << 16);
    ((uint2*)out)[(size_t)v * 64 + lane] = ov;
}

// ---------------- MFMA GEMM: C[M x 256] = op(A[M x K] @ Bt^T), A dual-segment ----------------
template <bool BIAS, bool TANH>
__global__ __launch_bounds__(256)
void mfma_gemm(const unsigned short* __restrict__ A0, const unsigned short* __restrict__ A1,
               int Ksplit, int K, const unsigned short* __restrict__ Bt,
               const float* __restrict__ bias, unsigned short* __restrict__ Cb, int M) {
    __shared__ char lds[16384];
    int tid = threadIdx.x, lane = tid & 63, w = tid >> 6;
    int row0 = blockIdx.y * 128, col0 = blockIdx.x * 128;
    int wr = w >> 1, wc = w & 1;
    f32x4 acc[4][4] = {};
    int nk = K >> 5;
    for (int ks = 0; ks < nk; ++ks) {
        int k0 = ks << 5;
        __syncthreads();
        #pragma unroll
        for (int j = 0; j < 4; ++j) {
            int ins = w + (j << 2);
            int lrow = ((ins & 7) << 4) + (lane >> 2);
            int p = lane & 3;
            int slog = p ^ ((lrow >> 1) & 3);
            char* ldst = lds + ((ins & 7) << 10) + ((ins >= 8) ? 8192 : 0);
            const unsigned short* src;
            if (ins < 8) {
                int grow = row0 + lrow;
                if (grow >= M) grow = M - 1;
                const unsigned short* Asrc; int kk, pitch;
                if (k0 < Ksplit) { Asrc = A0; kk = k0; pitch = Ksplit; }
                else             { Asrc = A1; kk = k0 - Ksplit; pitch = K - Ksplit; }
                src = Asrc + (size_t)grow * pitch + kk + (slog << 3);
            } else {
                int grow = col0 + lrow;
                src = Bt + (size_t)grow * K + k0 + (slog << 3);
            }
            gload_lds16(src, ldst);
        }
        asm volatile("s_waitcnt vmcnt(0)" ::: "memory");
        __syncthreads();
        int s = lane >> 4, r16 = lane & 15;
        bf16x8 a[4], b[4];
        #pragma unroll
        for (int m = 0; m < 4; ++m) a[m] = *(const bf16x8*)(lds + lds_off(wr * 64 + m * 16 + r16, s));
        #pragma unroll
        for (int n = 0; n < 4; ++n) b[n] = *(const bf16x8*)(lds + 8192 + lds_off(wc * 64 + n * 16 + r16, s));
        #pragma unroll
        for (int m = 0; m < 4; ++m)
            #pragma unroll
            for (int n = 0; n < 4; ++n)
                acc[m][n] = __builtin_amdgcn_mfma_f32_16x16x32_bf16(a[m], b[n], acc[m][n], 0, 0, 0);
    }
    int q = lane >> 4, r16 = lane & 15;
    float bv[4];
    #pragma unroll
    for (int n = 0; n < 4; ++n) bv[n] = BIAS ? bias[col0 + wc * 64 + n * 16 + r16] : 0.f;
    #pragma unroll
    for (int m = 0; m < 4; ++m) {
        #pragma unroll
        for (int i = 0; i < 4; ++i) {
            int row = row0 + wr * 64 + m * 16 + q * 4 + i;
            if (row >= M) continue;
            #pragma unroll
            for (int n = 0; n < 4; ++n) {
                int col = col0 + wc * 64 + n * 16 + r16;
                float v = acc[m][n][i];
                if (BIAS) v += bv[n];
                if (TANH) v = tanhf(v);
                Cb[(size_t)row * 256 + col] = f2bf(v);
            }
        }
    }
}

// ---------------- attention u: 16 lanes/node, online softmax ----------------
__global__ __launch_bounds__(256)
void k_attn_u2(const unsigned short* __restrict__ emb, const unsigned short* __restrict__ t,
               const float* __restrict__ p0, const float* __restrict__ p1,
               const float* __restrict__ p2, unsigned short* __restrict__ u) {
    int tid = threadIdx.x;
    int g = tid >> 4, l = tid & 15;
    int n = blockIdx.x * 16 + g;
    size_t eoff = (size_t)n * 256 + l * 16;
    const uint4* e16 = (const uint4*)(emb + eoff);
    uint4* u16 = (uint4*)(u + eoff);
    uint4 eb0 = e16[0], eb1 = e16[1];
    if (n >= P2_) { u16[0] = eb0; u16[1] = eb1; return; }
    float tv[16], ev[16];
    {
        const uint4* t16 = (const uint4*)(t + eoff);
        unpk8(t16[0], tv); unpk8(t16[1], tv + 8);
        unpk8(eb0, ev); unpk8(eb1, ev + 8);
    }
    float m = -3.0e38f, den = 0.f, o[16];
    #pragma unroll
    for (int i = 0; i < 16; i++) o[i] = 0.f;
    auto accum = [&](const float* sv) {
        float dt = 0.f;
        #pragma unroll
        for (int i = 0; i < 16; i++) dt += tv[i] * sv[i];
        dt += __shfl_xor(dt, 1);
        dt += __shfl_xor(dt, 2);
        dt += __shfl_xor(dt, 4);
        dt += __shfl_xor(dt, 8);
        float lg = dt * 0.0625f;
        float mn = fmaxf(m, lg);
        float s0 = expf(m - mn), s1 = expf(lg - mn);
        den = den * s0 + s1;
        #pragma unroll
        for (int i = 0; i < 16; i++) o[i] = o[i] * s0 + s1 * sv[i];
        m = mn;
    };
    auto accum_f32 = [&](const float* base) {
        float sv[16];
        const float4* b4 = (const float4*)(base + eoff);
        #pragma unroll
        for (int i = 0; i < 4; i++) {
            float4 q = b4[i];
            sv[4 * i] = q.x; sv[4 * i + 1] = q.y; sv[4 * i + 2] = q.z; sv[4 * i + 3] = q.w;
        }
        accum(sv);
    };
    if (n < P0_)      { accum_f32(p0); accum_f32(p1); accum_f32(p2); }
    else if (n < P1_) { accum_f32(p1); accum_f32(p2); }
    else              { accum_f32(p2); }
    accum(ev);
    float inv = 1.f / den;
    unsigned short h[16];
    #pragma unroll
    for (int i = 0; i < 16; i++) h[i] = f2bf(o[i] * inv);
    uint4 r0, r1;
    r0.x = h[0] | ((unsigned int)h[1] << 16);  r0.y = h[2] | ((unsigned int)h[3] << 16);
    r0.z = h[4] | ((unsigned int)h[5] << 16);  r0.w = h[6] | ((unsigned int)h[7] << 16);
    r1.x = h[8] | ((unsigned int)h[9] << 16);  r1.y = h[10] | ((unsigned int)h[11] << 16);
    r1.z = h[12] | ((unsigned int)h[13] << 16); r1.w = h[14] | ((unsigned int)h[15] << 16);
    u16[0] = r0; u16[1] = r1;
}

// ---------------- fused edge MLP via MFMA (read-once gather; optional fused bilinear sim) ----------------
template <bool SIM>
__global__ __launch_bounds__(256)
void mfma_edge(const unsigned short* __restrict__ srcemb, const unsigned short* __restrict__ gsrc,
               const int* __restrict__ es, const int* __restrict__ ed,
               const unsigned short* __restrict__ W1t, const float* __restrict__ b1,
               const float* __restrict__ w2, const float* __restrict__ sumb,
               float* __restrict__ a_pre, float* __restrict__ mlsc) {
    __shared__ char lds[8192 + 32768];
    __shared__ float red[64];
    int tid = threadIdx.x, lane = tid & 63, w = tid >> 6;
    int e0 = blockIdx.x * 64;
    int arow = tid >> 2, p = tid & 3;
    int ia = es[e0 + arow], ib = ed[e0 + arow];
    const unsigned short* ra = srcemb + (size_t)ia * 256;
    const unsigned short* rb = srcemb + (size_t)ib * 256;
    const unsigned short* rg = SIM ? (gsrc + (size_t)ia * 256) : nullptr;
    int slog = p ^ ((arow >> 1) & 3);
    if (tid < 64) red[tid] = 0.f;
    float simacc = 0.f;
    f32x4 acc[4][4] = {};
    for (int os = 0; os < 8; ++os) {
        int cb = (os << 5) + (slog << 3);
        __syncthreads();
        // A-stage: read each gathered row once per 32-col slice, emit mean & max slices
        {
            float fa[8], fb[8];
            uint4 ua = *(const uint4*)(ra + cb);
            uint4 ub = *(const uint4*)(rb + cb);
            unpk8(ua, fa); unpk8(ub, fb);
            bf16x8 vm, vx;
            #pragma unroll
            for (int i = 0; i < 8; i++) {
                vm[i] = (short)f2bf(0.5f * (fa[i] + fb[i]));
                vx[i] = (short)f2bf(fmaxf(fa[i], fb[i]));
            }
            *(bf16x8*)(lds + arow * 64 + (p << 4)) = vm;
            *(bf16x8*)(lds + 4096 + arow * 64 + (p << 4)) = vx;
            if (SIM) {
                float fg[8];
                uint4 ug = *(const uint4*)(rg + cb);
                unpk8(ug, fg);
                #pragma unroll
                for (int i = 0; i < 8; i++) simacc += fg[i] * fb[i];
            }
        }
        // B-stage: two k-slices (mean k-range os*32, max k-range 256+os*32)
        #pragma unroll
        for (int j = 0; j < 8; ++j) {
            int ins = (j << 2) + w;            // 0..31
            int half = ins >> 4;
            int lrow = ((ins & 15) << 4) + (lane >> 2);
            int pp = lane & 3;
            int sl = pp ^ ((lrow >> 1) & 3);
            const unsigned short* src = W1t + (size_t)lrow * 512 + (half << 8) + (os << 5) + (sl << 3);
            gload_lds16(src, lds + 8192 + (ins << 10));
        }
        asm volatile("s_waitcnt vmcnt(0)" ::: "memory");
        __syncthreads();
        int s = lane >> 4, r16 = lane & 15;
        #pragma unroll
        for (int half = 0; half < 2; ++half) {
            bf16x8 a[4], b[4];
            #pragma unroll
            for (int m2 = 0; m2 < 4; ++m2)
                a[m2] = *(const bf16x8*)(lds + half * 4096 + lds_off(m2 * 16 + r16, s));
            #pragma unroll
            for (int n2 = 0; n2 < 4; ++n2)
                b[n2] = *(const bf16x8*)(lds + 8192 + half * 16384 + lds_off(w * 64 + n2 * 16 + r16, s));
            #pragma unroll
            for (int m2 = 0; m2 < 4; ++m2)
                #pragma unroll
                for (int n2 = 0; n2 < 4; ++n2)
                    acc[m2][n2] = __builtin_amdgcn_mfma_f32_16x16x32_bf16(a[m2], b[n2], acc[m2][n2], 0, 0, 0);
        }
    }
    // epilogue: layer-2 dot, reduce to per-edge scalar
    int q = lane >> 4, r16 = lane & 15;
    float b1c[4], w2c[4];
    #pragma unroll
    for (int n2 = 0; n2 < 4; ++n2) {
        int c = w * 64 + n2 * 16 + r16;
        b1c[n2] = b1[c]; w2c[n2] = w2[c];
    }
    #pragma unroll
    for (int m2 = 0; m2 < 4; ++m2) {
        #pragma unroll
        for (int i = 0; i < 4; ++i) {
            int row = m2 * 16 + q * 4 + i;
            float ps = 0.f;
            #pragma unroll
            for (int n2 = 0; n2 < 4; ++n2) ps += tanhf(acc[m2][n2][i] + b1c[n2]) * w2c[n2];
            ps += __shfl_xor(ps, 1);
            ps += __shfl_xor(ps, 2);
            ps += __shfl_xor(ps, 4);
            ps += __shfl_xor(ps, 8);
            if (r16 == 0) atomicAdd(&red[row], ps);
        }
    }
    if (SIM) {
        simacc += __shfl_xor(simacc, 1);
        simacc += __shfl_xor(simacc, 2);
        if (p == 0) mlsc[e0 + arow] = 1.f / (1.f + expf(-(simacc + sumb[0])));
    }
    __syncthreads();
    if (tid < 64) a_pre[e0 + tid] = red[tid];
}

// ---------------- final ensemble ----------------
__global__ void k_final(const float* __restrict__ apml, const float* __restrict__ apms,
                        const float* __restrict__ mlsc, const float* __restrict__ mstr,
                        const float* __restrict__ pxtr, const int* __restrict__ index,
                        const float* __restrict__ mlb2, const float* __restrict__ msb2,
                        float* __restrict__ out) {
    int e = blockIdx.x * 256 + threadIdx.x;
    if (e >= E_) return;
    float aml = tanhf(apml[e] + mlb2[0]);
    float ams = tanhf(apms[e] + msb2[0]);
    float apx = PROXW;
    float m = fmaxf(aml, fmaxf(ams, apx));
    float wml = expf(aml - m), wms = expf(ams - m), wpx = expf(apx - m);
    float inv = 1.f / (wml + wms + wpx);
    int idx = index[e];
    float v = (mlsc[e] * wml + mstr[idx] * wms + pxtr[idx] * wpx) * inv;
    out[e] = fminf(fmaxf(v, 0.f), 1.f);
}

__global__ void k_sentinel(float* out, int n) {
    int i = blockIdx.x * 256 + threadIdx.x;
    if (i < n) out[i] = -12345.0f;
}

// ---------------- launch ----------------
extern "C" void kernel_launch(void* const* d_in, const int* in_sizes, int n_in,
                              void* d_out, int out_size, void* d_ws, size_t ws_size,
                              hipStream_t stream) {
    const float* x     = (const float*)d_in[0];
    const int*   mp    = (const int*)d_in[1];
    const int*   edges = (const int*)d_in[2];
    const int*   index = (const int*)d_in[3];
    const float* p0    = (const float*)d_in[4];
    const float* p1    = (const float*)d_in[5];
    const float* p2    = (const float*)d_in[6];
    const float* gc1W  = (const float*)d_in[7];
    const float* gc1b  = (const float*)d_in[8];
    const float* gc2W  = (const float*)d_in[9];
    const float* gc2b  = (const float*)d_in[10];
    const float* linW  = (const float*)d_in[11];
    const float* linb  = (const float*)d_in[12];
    const float* wlin  = (const float*)d_in[13];
    const float* blin  = (const float*)d_in[14];
    const float* wq    = (const float*)d_in[15];
    const float* wk    = (const float*)d_in[16];
    const float* wv    = (const float*)d_in[17];
    const float* mlw1  = (const float*)d_in[18];
    const float* mlb1  = (const float*)d_in[19];
    const float* mlw2  = (const float*)d_in[20];
    const float* mlb2  = (const float*)d_in[21];
    const float* msw1  = (const float*)d_in[22];
    const float* msb1  = (const float*)d_in[23];
    const float* msw2  = (const float*)d_in[24];
    const float* msb2  = (const float*)d_in[25];
    const float* msdrW = (const float*)d_in[26];
    const float* msdrb = (const float*)d_in[27];
    const float* logits = (const float*)d_in[28];
    const float* mstr  = (const float*)d_in[29];
    const float* pxtr  = (const float*)d_in[30];
    float* out = (float*)d_out;

    const int* src_mp = mp;
    const int* dst_mp = mp + EMP_;
    const int* es = edges;
    const int* ed = edges + E_;

    char* ws = (char*)d_ws;
    size_t off = 0;
    auto alloc = [&](size_t bytes) -> char* {
        off = (off + 255) & ~(size_t)255;
        char* r = ws + off;
        off += bytes;
        return r;
    };
    const size_t NODE_BF = (size_t)Nn_ * 256 * 2;
    unsigned short* W0 = (unsigned short*)alloc(NODE_BF);  // xb -> gb
    unsigned short* W1 = (unsigned short*)alloc(NODE_BF);  // xw1/xw2 -> logitsb
    unsigned short* W2 = (unsigned short*)alloc(NODE_BF);  // hb -> rb
    unsigned short* W3 = (unsigned short*)alloc(NODE_BF);  // embb
    unsigned short* W4 = (unsigned short*)alloc(NODE_BF);  // tb/ub
    unsigned short* W5 = (unsigned short*)alloc(NODE_BF);  // emb2b
    int*   cnt  = (int*)alloc((size_t)Nn_ * 4);
    int*   rowp = (int*)alloc((size_t)(Nn_ + 1) * 4);
    int*   fill = (int*)alloc((size_t)Nn_ * 4);
    int*   csr  = (int*)alloc((size_t)EMP_ * 4);
    float* dinv = (float*)alloc((size_t)Nn_ * 4);
    int*   bsum = (int*)alloc(512 * 4);
    float* Mqk  = (float*)alloc(65536 * 4);
    float* W2wf = (float*)alloc(65536 * 4);
    unsigned short* gc1Wt = (unsigned short*)alloc(65536 * 2);
    unsigned short* gc2Wt = (unsigned short*)alloc(65536 * 2);
    unsigned short* MqkT  = (unsigned short*)alloc(65536 * 2);
    unsigned short* Bt512 = (unsigned short*)alloc(131072 * 2);
    unsigned short* symb  = (unsigned short*)alloc(65536 * 2);
    unsigned short* msdrWt = (unsigned short*)alloc(16384 * 2);
    unsigned short* mlw1t = (unsigned short*)alloc(131072 * 2);
    unsigned short* msw1t = (unsigned short*)alloc(131072 * 2);
    float* apml = (float*)alloc((size_t)E_ * 4);
    float* apms = (float*)alloc((size_t)E_ * 4);
    float* mlsc = (float*)alloc((size_t)E_ * 4);
    float* sumb = (float*)alloc(256);

    if (off > ws_size) {
        k_sentinel<<<(E_ + 255) / 256, 256, 0, stream>>>(out, E_);
        return;
    }

    hipMemsetAsync(cnt, 0, (size_t)Nn_ * 4, stream);
    hipMemsetAsync(fill, 0, (size_t)Nn_ * 4, stream);

    const int NB = (Nn_ + 255) / 256;
    const int EB = (EMP_ + 255) / 256;

    // input conversions + weight prep
    k_cvt<<<30000, 256, 0, stream>>>(x, W0, Nn_ * 256 / 4);
    k_transpose_cvt<<<256, 256, 0, stream>>>(gc1W, gc1Wt, 256, 256);
    k_transpose_cvt<<<256, 256, 0, stream>>>(gc2W, gc2Wt, 256, 256);
    k_transpose_cvt<<<256, 256, 0, stream>>>(msdrW, msdrWt, 64, 256);
    k_transpose_cvt<<<256, 256, 0, stream>>>(mlw1, mlw1t, 512, 256);
    k_transpose_cvt<<<256, 256, 0, stream>>>(msw1, msw1t, 512, 256);
    k_sym_cvt<<<256, 256, 0, stream>>>(wlin, symb);
    k_sumb<<<1, 256, 0, stream>>>(blin, sumb);
    dim3 gSmall(4, 4);
    gemm_tiled<true><<<gSmall, 256, 0, stream>>>(wq, wk, Mqk, 256, 256, 256);
    gemm_tiled<false><<<gSmall, 256, 0, stream>>>(wv, linW + 256 * 256, W2wf, 256, 256, 256);
    k_transpose_cvt<<<256, 256, 0, stream>>>(Mqk, MqkT, 256, 256);
    k_bt512<<<512, 256, 0, stream>>>(linW, W2wf, Bt512);

    // CSR
    k_count<<<EB, 256, 0, stream>>>(dst_mp, cnt, EMP_);
    k_block_reduce<<<NB, 256, 0, stream>>>(cnt, bsum, Nn_);
    k_scan_bsum<<<1, 64, 0, stream>>>(bsum, NB);
    k_scan_final<<<NB, 256, 0, stream>>>(cnt, bsum, rowp, Nn_, EMP_);
    k_fill<<<EB, 256, 0, stream>>>(src_mp, dst_mp, rowp, fill, csr, EMP_);
    k_dinv<<<NB, 256, 0, stream>>>(cnt, dinv, Nn_);

    dim3 gFull(2, (Nn_ + 127) / 128);
    dim3 gT(2, (P2_ + 127) / 128);
    const int AGG_B = (Nn_ + 3) / 4;

    // GCN layer 1
    mfma_gemm<false, false><<<gFull, 256, 0, stream>>>(W0, W0, 256, 256, gc1Wt, nullptr, W1, Nn_);
    k_agg_bf<<<AGG_B, 256, 0, stream>>>(W1, rowp, csr, dinv, gc1b, W2);
    // GCN layer 2
    mfma_gemm<false, false><<<gFull, 256, 0, stream>>>(W2, W2, 256, 256, gc2Wt, nullptr, W1, Nn_);
    k_agg_bf<<<AGG_B, 256, 0, stream>>>(W1, rowp, csr, dinv, gc2b, W3);

    // attention: t = emb @ Mqk (rows < P2), then u (16 nodes/block)
    mfma_gemm<false, false><<<gT, 256, 0, stream>>>(W3, W3, 256, 256, MqkT, nullptr, W4, P2_);
    k_attn_u2<<<Nn_ / 16, 256, 0, stream>>>(W3, W4, p0, p1, p2, W4);

    // emb2 = tanh([emb|u] @ Bt512^T + linb)
    mfma_gemm<true, true><<<gFull, 256, 0, stream>>>(W3, W4, 256, 512, Bt512, linb, W5, Nn_);

    // g = emb2 @ sym
    mfma_gemm<false, false><<<gFull, 256, 0, stream>>>(W5, W5, 256, 256, symb, nullptr, W0, Nn_);

    // r = tanh(logits @ msdrW + msdrb)
    k_cvt<<<7500, 256, 0, stream>>>(logits, W1, Nn_ * 64 / 4);
    mfma_gemm<true, true><<<gFull, 256, 0, stream>>>(W1, W1, 64, 64, msdrWt, msdrb, W2, Nn_);

    // edge MLPs (+fused bilinear sim in the ml pass)
    mfma_edge<true><<<E_ / 64, 256, 0, stream>>>(W5, W0, es, ed, mlw1t, mlb1, mlw2, sumb, apml, mlsc);
    mfma_edge<false><<<E_ / 64, 256, 0, stream>>>(W2, nullptr, es, ed, msw1t, msb1, msw2, sumb, apms, nullptr);

    // final ensemble
    k_final<<<(E_ + 255) / 256, 256, 0, stream>>>(apml, apms, mlsc, mstr, pxtr, index, mlb2, msb2, out);
}

// Round 4
// 1050.490 us; speedup vs baseline: 3.8649x; 1.2126x over previous
//
#include <hip/hip_runtime.h>
#include <hip/hip_bf16.h>

// ---------------- constants ----------------
#define Nn_   120000
#define F_    256
#define H_    256
#define L_    64
#define EMP_  1000000
#define E_    200000
#define P0_   60000
#define P1_   80000
#define P2_   100000
#define PROXW 0.3f

typedef __attribute__((ext_vector_type(8))) short bf16x8;
typedef __attribute__((ext_vector_type(4))) float f32x4;

__device__ inline float bf2f(unsigned short u) {
    union { unsigned int i; float f; } x; x.i = ((unsigned int)u) << 16; return x.f;
}
__device__ inline unsigned short f2bf(float f) {
    union { float f; unsigned int i; } x; x.f = f;
    unsigned int r = x.i + 0x7fffu + ((x.i >> 16) & 1u);
    return (unsigned short)(r >> 16);
}
// tanh via native exp + rcp: 1 - 2/(e^{2x}+1). Exact at +-inf, ~1e-6 rel err.
__device__ inline float tanh_fast(float x) {
    float e = __expf(2.0f * x);
    return 1.0f - 2.0f * __builtin_amdgcn_rcpf(e + 1.0f);
}
__device__ inline float sigmoid_fast(float z) {
    return __builtin_amdgcn_rcpf(1.0f + __expf(-z));
}
__device__ inline int lds_off(int row, int s) {
    return row * 64 + ((s ^ ((row >> 1) & 3)) << 4);
}
__device__ inline void gload_lds16(const void* g, void* l) {
    __builtin_amdgcn_global_load_lds((const __attribute__((address_space(1))) void*)g,
                                     (__attribute__((address_space(3))) void*)l, 16, 0, 0);
}
__device__ inline void unpk8(uint4 u, float* o) {
    o[0] = bf2f(u.x & 0xffff); o[1] = bf2f(u.x >> 16);
    o[2] = bf2f(u.y & 0xffff); o[3] = bf2f(u.y >> 16);
    o[4] = bf2f(u.z & 0xffff); o[5] = bf2f(u.z >> 16);
    o[6] = bf2f(u.w & 0xffff); o[7] = bf2f(u.w >> 16);
}

// ---------------- CSR build ----------------
__global__ void k_count(const int* __restrict__ dst, int* __restrict__ cnt, int n) {
    int e = blockIdx.x * 256 + threadIdx.x;
    if (e < n) atomicAdd(&cnt[dst[e]], 1);
}
__global__ void k_block_reduce(const int* __restrict__ cnt, int* __restrict__ bsum, int n) {
    __shared__ int s[256];
    int i = blockIdx.x * 256 + threadIdx.x;
    s[threadIdx.x] = (i < n) ? cnt[i] : 0;
    __syncthreads();
    for (int o = 128; o > 0; o >>= 1) {
        if (threadIdx.x < o) s[threadIdx.x] += s[threadIdx.x + o];
        __syncthreads();
    }
    if (threadIdx.x == 0) bsum[blockIdx.x] = s[0];
}
__global__ void k_scan_bsum(int* bsum, int nb) {
    if (threadIdx.x == 0 && blockIdx.x == 0) {
        int acc = 0;
        for (int i = 0; i < nb; i++) { int v = bsum[i]; bsum[i] = acc; acc += v; }
    }
}
__global__ void k_scan_final(const int* __restrict__ cnt, const int* __restrict__ bsum,
                             int* __restrict__ rowp, int n, int etot) {
    __shared__ int s[256];
    int tid = threadIdx.x;
    int i = blockIdx.x * 256 + tid;
    int v = (i < n) ? cnt[i] : 0;
    s[tid] = v;
    __syncthreads();
    for (int o = 1; o < 256; o <<= 1) {
        int t = 0;
        if (tid >= o) t = s[tid - o];
        __syncthreads();
        s[tid] += t;
        __syncthreads();
    }
    if (i < n) rowp[i] = bsum[blockIdx.x] + s[tid] - v;
    if (i == 0 && blockIdx.x == 0) rowp[n] = etot;
}
__global__ void k_fill(const int* __restrict__ src, const int* __restrict__ dst,
                       const int* __restrict__ rowp, int* __restrict__ fill,
                       int* __restrict__ csr, int n) {
    int e = blockIdx.x * 256 + threadIdx.x;
    if (e < n) {
        int d = dst[e];
        int p = atomicAdd(&fill[d], 1);
        csr[rowp[d] + p] = src[e];
    }
}
__global__ void k_dinv(const int* __restrict__ cnt, float* __restrict__ dinv, int n) {
    int i = blockIdx.x * 256 + threadIdx.x;
    if (i < n) dinv[i] = rsqrtf((float)cnt[i] + 1.0f);
}

// ---------------- small f32 tiled GEMM (for 256^3 precomputes only) ----------------
#define TM 64
#define TN 64
#define TK 16
template <bool TRANSB>
__global__ void gemm_tiled(const float* __restrict__ A, const float* __restrict__ B,
                           float* __restrict__ C, int M, int K, int N) {
    __shared__ float As[TK][TM + 4];
    __shared__ float Bs[TK][TN + 4];
    int tid = threadIdx.x;
    int tx = tid & 15, ty = tid >> 4;
    int row0 = blockIdx.y * TM, col0 = blockIdx.x * TN;
    int lr = tid >> 2, lc4 = (tid & 3) * 4;
    float acc[4][4] = {};
    for (int k0 = 0; k0 < K; k0 += TK) {
        {
            int gr = row0 + lr;
            float4 v = make_float4(0.f, 0.f, 0.f, 0.f);
            if (gr < M) v = *(const float4*)(A + (size_t)gr * K + k0 + lc4);
            As[lc4 + 0][lr] = v.x; As[lc4 + 1][lr] = v.y;
            As[lc4 + 2][lr] = v.z; As[lc4 + 3][lr] = v.w;
        }
        {
            int n = tid & 63, kk0 = tid >> 6;
#pragma unroll
            for (int p = 0; p < 4; p++) {
                int kk = kk0 + p * 4;
                if (TRANSB) Bs[kk][n] = B[(size_t)(col0 + n) * K + k0 + kk];
                else        Bs[kk][n] = B[(size_t)(k0 + kk) * N + col0 + n];
            }
        }
        __syncthreads();
#pragma unroll
        for (int kk = 0; kk < TK; kk++) {
            float4 a = *(const float4*)&As[kk][ty * 4];
            float4 b = *(const float4*)&Bs[kk][tx * 4];
            float av[4] = {a.x, a.y, a.z, a.w};
            float bv[4] = {b.x, b.y, b.z, b.w};
#pragma unroll
            for (int i = 0; i < 4; i++)
#pragma unroll
                for (int j = 0; j < 4; j++) acc[i][j] += av[i] * bv[j];
        }
        __syncthreads();
    }
#pragma unroll
    for (int i = 0; i < 4; i++) {
        int r = row0 + ty * 4 + i;
        if (r >= M) continue;
#pragma unroll
        for (int j = 0; j < 4; j++) C[(size_t)r * N + col0 + tx * 4 + j] = acc[i][j];
    }
}

// ---------------- conversions / transposes ----------------
__global__ void k_cvt(const float* __restrict__ in, unsigned short* __restrict__ out, int n4) {
    int i = blockIdx.x * 256 + threadIdx.x;
    if (i >= n4) return;
    float4 v = ((const float4*)in)[i];
    ushort4 o;
    o.x = f2bf(v.x); o.y = f2bf(v.y); o.z = f2bf(v.z); o.w = f2bf(v.w);
    ((ushort4*)out)[i] = o;
}
__global__ void k_transpose_cvt(const float* __restrict__ W, unsigned short* __restrict__ Wt,
                                int R, int C) {
    int c = blockIdx.x;
    for (int r = threadIdx.x; r < R; r += 256)
        Wt[(size_t)c * R + r] = f2bf(W[(size_t)r * C + c]);
}
__global__ void k_sym_cvt(const float* __restrict__ W, unsigned short* __restrict__ symb) {
    int r = blockIdx.x, c = threadIdx.x;
    symb[r * 256 + c] = f2bf(0.5f * (W[r * 256 + c] + W[c * 256 + r]));
}
__global__ void k_bt512(const float* __restrict__ linW, const float* __restrict__ W2w,
                        unsigned short* __restrict__ Bt) {
    int idx = blockIdx.x * 256 + threadIdx.x;
    int n = idx >> 9, k = idx & 511;
    float v = (k < 256) ? linW[(size_t)k * 256 + n] : W2w[(size_t)(k - 256) * 256 + n];
    Bt[idx] = f2bf(v);
}
__global__ void k_sumb(const float* __restrict__ b, float* __restrict__ out) {
    __shared__ float s[256];
    int tid = threadIdx.x;
    s[tid] = b[tid];
    __syncthreads();
    for (int o = 128; o > 0; o >>= 1) {
        if (tid < o) s[tid] += s[tid + o];
        __syncthreads();
    }
    if (tid == 0) out[0] = s[0];
}

// ---------------- GCN aggregation: one wave per node, 1-deep neighbor prefetch ----------------
__global__ __launch_bounds__(256)
void k_agg_bf(const unsigned short* __restrict__ xw, const int* __restrict__ rowp,
              const int* __restrict__ csr, const float* __restrict__ dinv,
              const float* __restrict__ bias, unsigned short* __restrict__ out) {
    int w = threadIdx.x >> 6, lane = threadIdx.x & 63;
    int v = blockIdx.x * 4 + w;
    if (v >= Nn_) return;
    const uint2* x64 = (const uint2*)xw;
    float a0 = 0.f, a1 = 0.f, a2 = 0.f, a3 = 0.f;
    int beg = rowp[v], end = rowp[v + 1];
    uint2 un = make_uint2(0, 0); float dn = 0.f;
    if (beg < end) {
        int s0 = csr[beg];
        dn = dinv[s0];
        un = x64[(size_t)s0 * 64 + lane];
    }
    for (int p = beg; p < end; ++p) {
        uint2 uc = un; float dc = dn;
        if (p + 1 < end) {
            int s1 = csr[p + 1];
            dn = dinv[s1];
            un = x64[(size_t)s1 * 64 + lane];
        }
        a0 += bf2f(uc.x & 0xffff) * dc;
        a1 += bf2f(uc.x >> 16) * dc;
        a2 += bf2f(uc.y & 0xffff) * dc;
        a3 += bf2f(uc.y >> 16) * dc;
    }
    float dv = dinv[v];
    uint2 us = x64[(size_t)v * 64 + lane];
    a0 = a0 * dv + bf2f(us.x & 0xffff) * dv * dv;
    a1 = a1 * dv + bf2f(us.x >> 16) * dv * dv;
    a2 = a2 * dv + bf2f(us.y & 0xffff) * dv * dv;
    a3 = a3 * dv + bf2f(us.y >> 16) * dv * dv;
    int c0 = lane * 4;
    float4 bv = *(const float4*)(bias + c0);
    uint2 ov;
    ov.x = (unsigned int)f2bf(tanh_fast(a0 + bv.x)) |
           ((unsigned int)f2bf(tanh_fast(a1 + bv.y)) << 16);
    ov.y = (unsigned int)f2bf(tanh_fast(a2 + bv.z)) |
           ((unsigned int)f2bf(tanh_fast(a3 + bv.w)) << 16);
    ((uint2*)out)[(size_t)v * 64 + lane] = ov;
}

// ---------------- MFMA GEMM, double-buffered LDS + counted vmcnt ----------------
template <bool BIAS, bool TANH>
__global__ __launch_bounds__(256)
void mfma_gemm(const unsigned short* __restrict__ A0, const unsigned short* __restrict__ A1,
               int Ksplit, int K, const unsigned short* __restrict__ Bt,
               const float* __restrict__ bias, unsigned short* __restrict__ Cb, int M) {
    __shared__ char lds[2][16384];
    int tid = threadIdx.x, lane = tid & 63, w = tid >> 6;
    int row0 = blockIdx.y * 128, col0 = blockIdx.x * 128;
    int wr = w >> 1, wc = w & 1;
    f32x4 acc[4][4] = {};
    int nk = K >> 5;

    auto stage = [&](int ks, int buf) {
        int k0 = ks << 5;
        #pragma unroll
        for (int j = 0; j < 4; ++j) {
            int ins = w + (j << 2);
            int lrow = ((ins & 7) << 4) + (lane >> 2);
            int p = lane & 3;
            int slog = p ^ ((lrow >> 1) & 3);
            char* ldst = lds[buf] + ((ins & 7) << 10) + ((ins >= 8) ? 8192 : 0);
            const unsigned short* src;
            if (ins < 8) {
                int grow = row0 + lrow;
                if (grow >= M) grow = M - 1;
                const unsigned short* Asrc; int kk, pitch;
                if (k0 < Ksplit) { Asrc = A0; kk = k0; pitch = Ksplit; }
                else             { Asrc = A1; kk = k0 - Ksplit; pitch = K - Ksplit; }
                src = Asrc + (size_t)grow * pitch + kk + (slog << 3);
            } else {
                int grow = col0 + lrow;
                src = Bt + (size_t)grow * K + k0 + (slog << 3);
            }
            gload_lds16(src, ldst);
        }
    };

    stage(0, 0);
    for (int ks = 0; ks < nk; ++ks) {
        int cur = ks & 1;
        if (ks + 1 < nk) {
            stage(ks + 1, cur ^ 1);
            asm volatile("s_waitcnt vmcnt(4)" ::: "memory");
        } else {
            asm volatile("s_waitcnt vmcnt(0)" ::: "memory");
        }
        __syncthreads();
        int s = lane >> 4, r16 = lane & 15;
        bf16x8 a[4], b[4];
        #pragma unroll
        for (int m = 0; m < 4; ++m) a[m] = *(const bf16x8*)(lds[cur] + lds_off(wr * 64 + m * 16 + r16, s));
        #pragma unroll
        for (int n = 0; n < 4; ++n) b[n] = *(const bf16x8*)(lds[cur] + 8192 + lds_off(wc * 64 + n * 16 + r16, s));
        #pragma unroll
        for (int m = 0; m < 4; ++m)
            #pragma unroll
            for (int n = 0; n < 4; ++n)
                acc[m][n] = __builtin_amdgcn_mfma_f32_16x16x32_bf16(a[m], b[n], acc[m][n], 0, 0, 0);
        __syncthreads();
    }
    int q = lane >> 4, r16 = lane & 15;
    float bv[4];
    #pragma unroll
    for (int n = 0; n < 4; ++n) bv[n] = BIAS ? bias[col0 + wc * 64 + n * 16 + r16] : 0.f;
    #pragma unroll
    for (int m = 0; m < 4; ++m) {
        #pragma unroll
        for (int i = 0; i < 4; ++i) {
            int row = row0 + wr * 64 + m * 16 + q * 4 + i;
            if (row >= M) continue;
            #pragma unroll
            for (int n = 0; n < 4; ++n) {
                int col = col0 + wc * 64 + n * 16 + r16;
                float v = acc[m][n][i];
                if (BIAS) v += bv[n];
                if (TANH) v = tanh_fast(v);
                Cb[(size_t)row * 256 + col] = f2bf(v);
            }
        }
    }
}

// ---------------- attention u: 16 lanes/node, online softmax ----------------
__global__ __launch_bounds__(256)
void k_attn_u2(const unsigned short* __restrict__ emb, const unsigned short* __restrict__ t,
               const float* __restrict__ p0, const float* __restrict__ p1,
               const float* __restrict__ p2, unsigned short* __restrict__ u) {
    int tid = threadIdx.x;
    int g = tid >> 4, l = tid & 15;
    int n = blockIdx.x * 16 + g;
    size_t eoff = (size_t)n * 256 + l * 16;
    const uint4* e16 = (const uint4*)(emb + eoff);
    uint4* u16 = (uint4*)(u + eoff);
    uint4 eb0 = e16[0], eb1 = e16[1];
    if (n >= P2_) { u16[0] = eb0; u16[1] = eb1; return; }
    float tv[16], ev[16];
    {
        const uint4* t16 = (const uint4*)(t + eoff);
        unpk8(t16[0], tv); unpk8(t16[1], tv + 8);
        unpk8(eb0, ev); unpk8(eb1, ev + 8);
    }
    float m = -3.0e38f, den = 0.f, o[16];
    #pragma unroll
    for (int i = 0; i < 16; i++) o[i] = 0.f;
    auto accum = [&](const float* sv) {
        float dt = 0.f;
        #pragma unroll
        for (int i = 0; i < 16; i++) dt += tv[i] * sv[i];
        dt += __shfl_xor(dt, 1);
        dt += __shfl_xor(dt, 2);
        dt += __shfl_xor(dt, 4);
        dt += __shfl_xor(dt, 8);
        float lg = dt * 0.0625f;
        float mn = fmaxf(m, lg);
        float s0 = __expf(m - mn), s1 = __expf(lg - mn);
        den = den * s0 + s1;
        #pragma unroll
        for (int i = 0; i < 16; i++) o[i] = o[i] * s0 + s1 * sv[i];
        m = mn;
    };
    auto accum_f32 = [&](const float* base) {
        float sv[16];
        const float4* b4 = (const float4*)(base + eoff);
        #pragma unroll
        for (int i = 0; i < 4; i++) {
            float4 q = b4[i];
            sv[4 * i] = q.x; sv[4 * i + 1] = q.y; sv[4 * i + 2] = q.z; sv[4 * i + 3] = q.w;
        }
        accum(sv);
    };
    if (n < P0_)      { accum_f32(p0); accum_f32(p1); accum_f32(p2); }
    else if (n < P1_) { accum_f32(p1); accum_f32(p2); }
    else              { accum_f32(p2); }
    accum(ev);
    float inv = __builtin_amdgcn_rcpf(den);
    unsigned short h[16];
    #pragma unroll
    for (int i = 0; i < 16; i++) h[i] = f2bf(o[i] * inv);
    uint4 r0, r1;
    r0.x = h[0] | ((unsigned int)h[1] << 16);  r0.y = h[2] | ((unsigned int)h[3] << 16);
    r0.z = h[4] | ((unsigned int)h[5] << 16);  r0.w = h[6] | ((unsigned int)h[7] << 16);
    r1.x = h[8] | ((unsigned int)h[9] << 16);  r1.y = h[10] | ((unsigned int)h[11] << 16);
    r1.z = h[12] | ((unsigned int)h[13] << 16); r1.w = h[14] | ((unsigned int)h[15] << 16);
    u16[0] = r0; u16[1] = r1;
}

// ---------------- fused edge MLP via MFMA, pipelined gather ----------------
template <bool SIM>
__global__ __launch_bounds__(256)
void mfma_edge(const unsigned short* __restrict__ srcemb, const unsigned short* __restrict__ gsrc,
               const int* __restrict__ es, const int* __restrict__ ed,
               const unsigned short* __restrict__ W1t, const float* __restrict__ b1,
               const float* __restrict__ w2, const float* __restrict__ sumb,
               float* __restrict__ a_pre, float* __restrict__ mlsc) {
    __shared__ char lds[8192 + 32768];
    __shared__ float red[64];
    int tid = threadIdx.x, lane = tid & 63, w = tid >> 6;
    int e0 = blockIdx.x * 64;
    int arow = tid >> 2, p = tid & 3;
    int ia = es[e0 + arow], ib = ed[e0 + arow];
    const unsigned short* ra = srcemb + (size_t)ia * 256;
    const unsigned short* rb = srcemb + (size_t)ib * 256;
    const unsigned short* rg = SIM ? (gsrc + (size_t)ia * 256) : nullptr;
    int slog = p ^ ((arow >> 1) & 3);
    if (tid < 64) red[tid] = 0.f;
    float simacc = 0.f;
    f32x4 acc[4][4] = {};
    // prologue: prefetch step-0 A slices into registers
    int cbp = slog << 3;
    uint4 pa = *(const uint4*)(ra + cbp);
    uint4 pb = *(const uint4*)(rb + cbp);
    uint4 pg = make_uint4(0, 0, 0, 0);
    if (SIM) pg = *(const uint4*)(rg + cbp);
    for (int os = 0; os < 8; ++os) {
        __syncthreads();   // prev MFMA done reading LDS
        // A convert + swizzled LDS write (compiler waits on pa/pb/pg here)
        {
            float fa[8], fb[8];
            unpk8(pa, fa); unpk8(pb, fb);
            bf16x8 vm, vx;
            #pragma unroll
            for (int i = 0; i < 8; i++) {
                vm[i] = (short)f2bf(0.5f * (fa[i] + fb[i]));
                vx[i] = (short)f2bf(fmaxf(fa[i], fb[i]));
            }
            *(bf16x8*)(lds + arow * 64 + (p << 4)) = vm;
            *(bf16x8*)(lds + 4096 + arow * 64 + (p << 4)) = vx;
            if (SIM) {
                float fg[8];
                unpk8(pg, fg);
                #pragma unroll
                for (int i = 0; i < 8; i++) simacc += fg[i] * fb[i];
            }
        }
        // B stage: 32 x 1KB rows of W1t k-slices (8 gload_lds per thread)
        #pragma unroll
        for (int j = 0; j < 8; ++j) {
            int ins = (j << 2) + w;
            int half = ins >> 4;
            int lrow = ((ins & 15) << 4) + (lane >> 2);
            int pp = lane & 3;
            int sl = pp ^ ((lrow >> 1) & 3);
            const unsigned short* src = W1t + (size_t)lrow * 512 + (half << 8) + (os << 5) + (sl << 3);
            gload_lds16(src, lds + 8192 + (ins << 10));
        }
        // A prefetch for step os+1 (stays in flight across the wait)
        if (os < 7) {
            int cb = ((os + 1) << 5) + (slog << 3);
            pa = *(const uint4*)(ra + cb);
            pb = *(const uint4*)(rb + cb);
            if (SIM) pg = *(const uint4*)(rg + cb);
            if (SIM) asm volatile("s_waitcnt vmcnt(3)" ::: "memory");
            else     asm volatile("s_waitcnt vmcnt(2)" ::: "memory");
        } else {
            asm volatile("s_waitcnt vmcnt(0)" ::: "memory");
        }
        __syncthreads();
        int s = lane >> 4, r16 = lane & 15;
        #pragma unroll
        for (int half = 0; half < 2; ++half) {
            bf16x8 a[4], b[4];
            #pragma unroll
            for (int m2 = 0; m2 < 4; ++m2)
                a[m2] = *(const bf16x8*)(lds + half * 4096 + lds_off(m2 * 16 + r16, s));
            #pragma unroll
            for (int n2 = 0; n2 < 4; ++n2)
                b[n2] = *(const bf16x8*)(lds + 8192 + half * 16384 + lds_off(w * 64 + n2 * 16 + r16, s));
            #pragma unroll
            for (int m2 = 0; m2 < 4; ++m2)
                #pragma unroll
                for (int n2 = 0; n2 < 4; ++n2)
                    acc[m2][n2] = __builtin_amdgcn_mfma_f32_16x16x32_bf16(a[m2], b[n2], acc[m2][n2], 0, 0, 0);
        }
    }
    // epilogue: layer-2 dot with fast tanh, reduce to per-edge scalar
    int q = lane >> 4, r16 = lane & 15;
    float b1c[4], w2c[4];
    #pragma unroll
    for (int n2 = 0; n2 < 4; ++n2) {
        int c = w * 64 + n2 * 16 + r16;
        b1c[n2] = b1[c]; w2c[n2] = w2[c];
    }
    #pragma unroll
    for (int m2 = 0; m2 < 4; ++m2) {
        #pragma unroll
        for (int i = 0; i < 4; ++i) {
            int row = m2 * 16 + q * 4 + i;
            float ps = 0.f;
            #pragma unroll
            for (int n2 = 0; n2 < 4; ++n2) ps += tanh_fast(acc[m2][n2][i] + b1c[n2]) * w2c[n2];
            ps += __shfl_xor(ps, 1);
            ps += __shfl_xor(ps, 2);
            ps += __shfl_xor(ps, 4);
            ps += __shfl_xor(ps, 8);
            if (r16 == 0) atomicAdd(&red[row], ps);
        }
    }
    if (SIM) {
        simacc += __shfl_xor(simacc, 1);
        simacc += __shfl_xor(simacc, 2);
        if (p == 0) mlsc[e0 + arow] = sigmoid_fast(simacc + sumb[0]);
    }
    __syncthreads();
    if (tid < 64) a_pre[e0 + tid] = red[tid];
}

// ---------------- final ensemble ----------------
__global__ void k_final(const float* __restrict__ apml, const float* __restrict__ apms,
                        const float* __restrict__ mlsc, const float* __restrict__ mstr,
                        const float* __restrict__ pxtr, const int* __restrict__ index,
                        const float* __restrict__ mlb2, const float* __restrict__ msb2,
                        float* __restrict__ out) {
    int e = blockIdx.x * 256 + threadIdx.x;
    if (e >= E_) return;
    float aml = tanh_fast(apml[e] + mlb2[0]);
    float ams = tanh_fast(apms[e] + msb2[0]);
    float apx = PROXW;
    float m = fmaxf(aml, fmaxf(ams, apx));
    float wml = __expf(aml - m), wms = __expf(ams - m), wpx = __expf(apx - m);
    float inv = __builtin_amdgcn_rcpf(wml + wms + wpx);
    int idx = index[e];
    float v = (mlsc[e] * wml + mstr[idx] * wms + pxtr[idx] * wpx) * inv;
    out[e] = fminf(fmaxf(v, 0.f), 1.f);
}

__global__ void k_sentinel(float* out, int n) {
    int i = blockIdx.x * 256 + threadIdx.x;
    if (i < n) out[i] = -12345.0f;
}

// ---------------- launch ----------------
extern "C" void kernel_launch(void* const* d_in, const int* in_sizes, int n_in,
                              void* d_out, int out_size, void* d_ws, size_t ws_size,
                              hipStream_t stream) {
    const float* x     = (const float*)d_in[0];
    const int*   mp    = (const int*)d_in[1];
    const int*   edges = (const int*)d_in[2];
    const int*   index = (const int*)d_in[3];
    const float* p0    = (const float*)d_in[4];
    const float* p1    = (const float*)d_in[5];
    const float* p2    = (const float*)d_in[6];
    const float* gc1W  = (const float*)d_in[7];
    const float* gc1b  = (const float*)d_in[8];
    const float* gc2W  = (const float*)d_in[9];
    const float* gc2b  = (const float*)d_in[10];
    const float* linW  = (const float*)d_in[11];
    const float* linb  = (const float*)d_in[12];
    const float* wlin  = (const float*)d_in[13];
    const float* blin  = (const float*)d_in[14];
    const float* wq    = (const float*)d_in[15];
    const float* wk    = (const float*)d_in[16];
    const float* wv    = (const float*)d_in[17];
    const float* mlw1  = (const float*)d_in[18];
    const float* mlb1  = (const float*)d_in[19];
    const float* mlw2  = (const float*)d_in[20];
    const float* mlb2  = (const float*)d_in[21];
    const float* msw1  = (const float*)d_in[22];
    const float* msb1  = (const float*)d_in[23];
    const float* msw2  = (const float*)d_in[24];
    const float* msb2  = (const float*)d_in[25];
    const float* msdrW = (const float*)d_in[26];
    const float* msdrb = (const float*)d_in[27];
    const float* logits = (const float*)d_in[28];
    const float* mstr  = (const float*)d_in[29];
    const float* pxtr  = (const float*)d_in[30];
    float* out = (float*)d_out;

    const int* src_mp = mp;
    const int* dst_mp = mp + EMP_;
    const int* es = edges;
    const int* ed = edges + E_;

    char* ws = (char*)d_ws;
    size_t off = 0;
    auto alloc = [&](size_t bytes) -> char* {
        off = (off + 255) & ~(size_t)255;
        char* r = ws + off;
        off += bytes;
        return r;
    };
    const size_t NODE_BF = (size_t)Nn_ * 256 * 2;
    unsigned short* W0 = (unsigned short*)alloc(NODE_BF);  // xb -> gb
    unsigned short* W1 = (unsigned short*)alloc(NODE_BF);  // xw1/xw2 -> logitsb
    unsigned short* W2 = (unsigned short*)alloc(NODE_BF);  // hb -> rb
    unsigned short* W3 = (unsigned short*)alloc(NODE_BF);  // embb
    unsigned short* W4 = (unsigned short*)alloc(NODE_BF);  // tb/ub
    unsigned short* W5 = (unsigned short*)alloc(NODE_BF);  // emb2b
    int*   cnt  = (int*)alloc((size_t)Nn_ * 4);
    int*   rowp = (int*)alloc((size_t)(Nn_ + 1) * 4);
    int*   fill = (int*)alloc((size_t)Nn_ * 4);
    int*   csr  = (int*)alloc((size_t)EMP_ * 4);
    float* dinv = (float*)alloc((size_t)Nn_ * 4);
    int*   bsum = (int*)alloc(512 * 4);
    float* Mqk  = (float*)alloc(65536 * 4);
    float* W2wf = (float*)alloc(65536 * 4);
    unsigned short* gc1Wt = (unsigned short*)alloc(65536 * 2);
    unsigned short* gc2Wt = (unsigned short*)alloc(65536 * 2);
    unsigned short* MqkT  = (unsigned short*)alloc(65536 * 2);
    unsigned short* Bt512 = (unsigned short*)alloc(131072 * 2);
    unsigned short* symb  = (unsigned short*)alloc(65536 * 2);
    unsigned short* msdrWt = (unsigned short*)alloc(16384 * 2);
    unsigned short* mlw1t = (unsigned short*)alloc(131072 * 2);
    unsigned short* msw1t = (unsigned short*)alloc(131072 * 2);
    float* apml = (float*)alloc((size_t)E_ * 4);
    float* apms = (float*)alloc((size_t)E_ * 4);
    float* mlsc = (float*)alloc((size_t)E_ * 4);
    float* sumb = (float*)alloc(256);

    if (off > ws_size) {
        k_sentinel<<<(E_ + 255) / 256, 256, 0, stream>>>(out, E_);
        return;
    }

    hipMemsetAsync(cnt, 0, (size_t)Nn_ * 4, stream);
    hipMemsetAsync(fill, 0, (size_t)Nn_ * 4, stream);

    const int NB = (Nn_ + 255) / 256;
    const int EB = (EMP_ + 255) / 256;

    // input conversions + weight prep
    k_cvt<<<30000, 256, 0, stream>>>(x, W0, Nn_ * 256 / 4);
    k_transpose_cvt<<<256, 256, 0, stream>>>(gc1W, gc1Wt, 256, 256);
    k_transpose_cvt<<<256, 256, 0, stream>>>(gc2W, gc2Wt, 256, 256);
    k_transpose_cvt<<<256, 256, 0, stream>>>(msdrW, msdrWt, 64, 256);
    k_transpose_cvt<<<256, 256, 0, stream>>>(mlw1, mlw1t, 512, 256);
    k_transpose_cvt<<<256, 256, 0, stream>>>(msw1, msw1t, 512, 256);
    k_sym_cvt<<<256, 256, 0, stream>>>(wlin, symb);
    k_sumb<<<1, 256, 0, stream>>>(blin, sumb);
    dim3 gSmall(4, 4);
    gemm_tiled<true><<<gSmall, 256, 0, stream>>>(wq, wk, Mqk, 256, 256, 256);
    gemm_tiled<false><<<gSmall, 256, 0, stream>>>(wv, linW + 256 * 256, W2wf, 256, 256, 256);
    k_transpose_cvt<<<256, 256, 0, stream>>>(Mqk, MqkT, 256, 256);
    k_bt512<<<512, 256, 0, stream>>>(linW, W2wf, Bt512);

    // CSR
    k_count<<<EB, 256, 0, stream>>>(dst_mp, cnt, EMP_);
    k_block_reduce<<<NB, 256, 0, stream>>>(cnt, bsum, Nn_);
    k_scan_bsum<<<1, 64, 0, stream>>>(bsum, NB);
    k_scan_final<<<NB, 256, 0, stream>>>(cnt, bsum, rowp, Nn_, EMP_);
    k_fill<<<EB, 256, 0, stream>>>(src_mp, dst_mp, rowp, fill, csr, EMP_);
    k_dinv<<<NB, 256, 0, stream>>>(cnt, dinv, Nn_);

    dim3 gFull(2, (Nn_ + 127) / 128);
    dim3 gT(2, (P2_ + 127) / 128);
    const int AGG_B = (Nn_ + 3) / 4;

    // GCN layer 1
    mfma_gemm<false, false><<<gFull, 256, 0, stream>>>(W0, W0, 256, 256, gc1Wt, nullptr, W1, Nn_);
    k_agg_bf<<<AGG_B, 256, 0, stream>>>(W1, rowp, csr, dinv, gc1b, W2);
    // GCN layer 2
    mfma_gemm<false, false><<<gFull, 256, 0, stream>>>(W2, W2, 256, 256, gc2Wt, nullptr, W1, Nn_);
    k_agg_bf<<<AGG_B, 256, 0, stream>>>(W1, rowp, csr, dinv, gc2b, W3);

    // attention: t = emb @ Mqk (rows < P2), then u (16 nodes/block)
    mfma_gemm<false, false><<<gT, 256, 0, stream>>>(W3, W3, 256, 256, MqkT, nullptr, W4, P2_);
    k_attn_u2<<<Nn_ / 16, 256, 0, stream>>>(W3, W4, p0, p1, p2, W4);

    // emb2 = tanh([emb|u] @ Bt512^T + linb)
    mfma_gemm<true, true><<<gFull, 256, 0, stream>>>(W3, W4, 256, 512, Bt512, linb, W5, Nn_);

    // g = emb2 @ sym
    mfma_gemm<false, false><<<gFull, 256, 0, stream>>>(W5, W5, 256, 256, symb, nullptr, W0, Nn_);

    // r = tanh(logits @ msdrW + msdrb)
    k_cvt<<<7500, 256, 0, stream>>>(logits, W1, Nn_ * 64 / 4);
    mfma_gemm<true, true><<<gFull, 256, 0, stream>>>(W1, W1, 64, 64, msdrWt, msdrb, W2, Nn_);

    // edge MLPs (+fused bilinear sim in the ml pass)
    mfma_edge<true><<<E_ / 64, 256, 0, stream>>>(W5, W0, es, ed, mlw1t, mlb1, mlw2, sumb, apml, mlsc);
    mfma_edge<false><<<E_ / 64, 256, 0, stream>>>(W2, nullptr, es, ed, msw1t, msb1, msw2, sumb, apms, nullptr);

    // final ensemble
    k_final<<<(E_ + 255) / 256, 256, 0, stream>>>(apml, apms, mlsc, mstr, pxtr, index, mlb2, msb2, out);
}